// Round 11
// baseline (325.619 us; speedup 1.0000x reference)
//
#include <hip/hip_runtime.h>

#define LBL 8
#define NBMAX 128
#define BSH 9            // 512 dsts per bucket
#define BCAP 8192        // LDS sort capacity per bucket (mean ~5100)
#define DBMAX 64         // degree-sort buckets

typedef __attribute__((ext_vector_type(8))) short short8;
typedef __attribute__((ext_vector_type(4))) float f32x4;

__device__ __forceinline__ uint f2bf(float x) {
    uint u = __float_as_uint(x);
    return (u + 0x7fffu + ((u >> 16) & 1u)) >> 16;
}
__device__ __forceinline__ float bflo(uint v) { return __uint_as_float(v << 16); }
__device__ __forceinline__ float bfhi(uint v) { return __uint_as_float(v & 0xffff0000u); }

// async global->LDS 16B per lane: dest = lds_base(wave-uniform) + lane*16
__device__ __forceinline__ void gload16(const ushort* g, ushort* l) {
    __builtin_amdgcn_global_load_lds((const __attribute__((address_space(1))) uint*)g,
                                     (__attribute__((address_space(3))) uint*)l, 16, 0, 0);
}

// ---------------- fp32 -> bf16 conversion (both node types, one dispatch) ----------------
__global__ void f2b2(const float4* __restrict__ x0, const float4* __restrict__ x1,
                     uint2* __restrict__ o0, uint2* __restrict__ o1, int n4) {
    int y = blockIdx.y;
    const float4* in = y ? x1 : x0;
    uint2* out = y ? o1 : o0;
    int i = blockIdx.x * blockDim.x + threadIdx.x;
    int stride = gridDim.x * blockDim.x;
    for (; i < n4; i += stride) {
        float4 v = in[i];
        uint2 o;
        o.x = f2bf(v.x) | (f2bf(v.y) << 16);
        o.y = f2bf(v.z) | (f2bf(v.w) << 16);
        out[i] = o;
    }
}

// ---------------- CSR build via two-pass counting sort (packed 4B records) ----------------

__global__ void bhist3(const int* __restrict__ e0, const int* __restrict__ e1,
                       const int* __restrict__ e2, int E, int NB, int* __restrict__ bcnt) {
    int m = blockIdx.y;
    const int* dst = (m == 0 ? e0 : (m == 1 ? e1 : e2)) + E;
    __shared__ int h[NBMAX];
    int tid = threadIdx.x;
    if (tid < NB) h[tid] = 0;
    __syncthreads();
    int i = blockIdx.x * blockDim.x + tid, st = gridDim.x * blockDim.x;
    for (; i < E; i += st) atomicAdd(&h[dst[i] >> BSH], 1);
    __syncthreads();
    if (tid < NB && h[tid]) atomicAdd(&bcnt[m * NB + tid], h[tid]);
}

__global__ void bscan(const int* __restrict__ bcnt, int* __restrict__ bso,
                      int* __restrict__ gcur, int NB) {
    int m = threadIdx.x;
    if (m >= 3) return;
    int acc = 0;
    for (int b = 0; b < NB; ++b) {
        bso[m * (NB + 1) + b] = acc;
        gcur[m * NB + b] = acc;
        acc += bcnt[m * NB + b];
    }
    bso[m * (NB + 1) + NB] = acc;
}

// record: src (16b) | dst-low-9 << 16   (requires N <= 65536)
#define BIN_CH 16
__global__ __launch_bounds__(256) void bin3(const int* __restrict__ e0, const int* __restrict__ e1,
                                            const int* __restrict__ e2, int E, int NB,
                                            int* __restrict__ gcur, uint* __restrict__ pairs) {
    int m = blockIdx.y;
    const int* eb = (m == 0 ? e0 : (m == 1 ? e1 : e2));
    const int* src = eb;
    const int* dst = eb + E;
    uint* pp = pairs + (size_t)m * E;
    int* gc = gcur + m * NB;
    __shared__ int h[NBMAX], base[NBMAX], pos[NBMAX];
    int tid = threadIdx.x;
    if (tid < NB) { h[tid] = 0; pos[tid] = 0; }
    __syncthreads();
    int i0 = blockIdx.x * (256 * BIN_CH);
    uint pk[BIN_CH];
    int bk[BIN_CH];
    #pragma unroll
    for (int u = 0; u < BIN_CH; ++u) {
        int i = i0 + u * 256 + tid;
        bk[u] = -1;
        if (i < E) {
            int s = src[i], d = dst[i];
            bk[u] = d >> BSH;
            pk[u] = (uint)s | ((uint)(d & ((1 << BSH) - 1)) << 16);
            atomicAdd(&h[bk[u]], 1);
        }
    }
    __syncthreads();
    if (tid < NB && h[tid]) base[tid] = atomicAdd(&gc[tid], h[tid]);
    __syncthreads();
    #pragma unroll
    for (int u = 0; u < BIN_CH; ++u) {
        if (bk[u] >= 0) {
            int p = base[bk[u]] + atomicAdd(&pos[bk[u]], 1);
            pp[p] = pk[u];
        }
    }
}

__global__ __launch_bounds__(256) void csr3(const uint* __restrict__ pairs, const int* __restrict__ bso,
                                            int E, int N, int NB,
                                            int* __restrict__ offs, int* __restrict__ srcs) {
    int m = blockIdx.y, b = blockIdx.x;
    const uint* pp = pairs + (size_t)m * E;
    int gstart = bso[m * (NB + 1) + b];
    int gend = bso[m * (NB + 1) + b + 1];
    int cnt = gend - gstart;
    if (cnt > BCAP) cnt = BCAP;
    int d0 = b << BSH;
    int dcnt = N - d0;
    if (dcnt > (1 << BSH)) dcnt = 1 << BSH;

    __shared__ int hist[1 << BSH], po[1 << BSH], off0[1 << BSH];
    __shared__ int lsort[BCAP];
    __shared__ int wsum[4];
    int tid = threadIdx.x;
    hist[tid] = 0;
    hist[tid + 256] = 0;
    __syncthreads();
    for (int i = tid; i < cnt; i += 256) atomicAdd(&hist[pp[gstart + i] >> 16], 1);
    __syncthreads();
    int a = hist[2 * tid], b2 = hist[2 * tid + 1];
    int s = a + b2;
    int lane = tid & 63, w = tid >> 6;
    #pragma unroll
    for (int o = 1; o < 64; o <<= 1) {
        int v = __shfl_up(s, o, 64);
        if (lane >= o) s += v;
    }
    if (lane == 63) wsum[w] = s;
    __syncthreads();
    int wp = 0;
    #pragma unroll
    for (int q = 0; q < 4; ++q)
        if (q < w) wp += wsum[q];
    int excl = wp + s - a - b2;
    off0[2 * tid] = excl; off0[2 * tid + 1] = excl + a;
    po[2 * tid] = excl;   po[2 * tid + 1] = excl + a;
    __syncthreads();
    for (int j = tid; j < dcnt; j += 256) offs[(size_t)m * (N + 1) + d0 + j] = gstart + off0[j];
    if (b == NB - 1 && tid == 0) offs[(size_t)m * (N + 1) + N] = bso[m * (NB + 1) + NB];
    for (int i = tid; i < cnt; i += 256) {
        uint e = pp[gstart + i];
        int p = atomicAdd(&po[e >> 16], 1);
        if (p < BCAP) lsort[p] = (int)(e & 0xffffu);
    }
    __syncthreads();
    for (int i = tid; i < cnt; i += 256) srcs[(size_t)m * E + gstart + i] = lsort[i];
}

// ---------------- degree-sort permutation (counting sort, 64 buckets) ----------------
__global__ void dhist3(const int* __restrict__ offs, int* __restrict__ dcnt, int N) {
    int m = blockIdx.y;
    const int* off = offs + (size_t)m * (N + 1);
    __shared__ int h[DBMAX];
    int tid = threadIdx.x;
    if (tid < DBMAX) h[tid] = 0;
    __syncthreads();
    int i = blockIdx.x * blockDim.x + tid, st = gridDim.x * blockDim.x;
    for (; i < N; i += st) {
        int d = off[i + 1] - off[i];
        atomicAdd(&h[d < DBMAX ? d : DBMAX - 1], 1);
    }
    __syncthreads();
    if (tid < DBMAX && h[tid]) atomicAdd(&dcnt[m * DBMAX + tid], h[tid]);
}

__global__ void dscan(const int* __restrict__ dcnt, int* __restrict__ dcur) {
    int m = threadIdx.x;
    if (m >= 3) return;
    int acc = 0;
    for (int b = 0; b < DBMAX; ++b) {
        dcur[m * DBMAX + b] = acc;
        acc += dcnt[m * DBMAX + b];
    }
}

#define DF_CH 8
__global__ __launch_bounds__(256) void dfill3(const int* __restrict__ offs, int* __restrict__ dcur,
                                              int* __restrict__ perm, int N) {
    int m = blockIdx.y;
    const int* off = offs + (size_t)m * (N + 1);
    int* dc = dcur + m * DBMAX;
    int* pm = perm + (size_t)m * N;
    __shared__ int h[DBMAX], base[DBMAX], pos[DBMAX];
    int tid = threadIdx.x;
    if (tid < DBMAX) { h[tid] = 0; pos[tid] = 0; }
    __syncthreads();
    int i0 = blockIdx.x * (256 * DF_CH);
    int bk[DF_CH];
    #pragma unroll
    for (int u = 0; u < DF_CH; ++u) {
        int i = i0 + u * 256 + tid;
        bk[u] = -1;
        if (i < N) {
            int d = off[i + 1] - off[i];
            bk[u] = d < DBMAX ? d : DBMAX - 1;
            atomicAdd(&h[bk[u]], 1);
        }
    }
    __syncthreads();
    if (tid < DBMAX && h[tid]) base[tid] = atomicAdd(&dc[tid], h[tid]);
    __syncthreads();
    #pragma unroll
    for (int u = 0; u < DF_CH; ++u) {
        if (bk[u] >= 0) {
            int p = base[bk[u]] + atomicAdd(&pos[bk[u]], 1);
            pm[p] = i0 + u * 256 + tid;
        }
    }
}

// ---------------- segment mean: 4 rows/wave via degree-sorted perm ----------------
__global__ void agg3(const ushort* __restrict__ s0, const ushort* __restrict__ s1,
                     const ushort* __restrict__ s2,
                     uint* __restrict__ o0, uint* __restrict__ o1, uint* __restrict__ o2,
                     const int* __restrict__ offs, const int* __restrict__ srcs,
                     const int* __restrict__ perm, int n, int E) {
    int m = blockIdx.y;
    const uint4* x = (const uint4*)(m == 0 ? s0 : (m == 1 ? s1 : s2));
    uint4* o = (uint4*)(m == 0 ? o0 : (m == 1 ? o1 : o2));
    const int* off = offs + (size_t)m * (n + 1);
    const int* sl = srcs + (size_t)m * E;
    const int* pm = perm + (size_t)m * n;

    int tid = threadIdx.x;
    int l16 = tid & 15;
    int gid = blockIdx.x * 16 + (tid >> 4);
    if (gid >= n) return;
    int row = pm[gid];                 // degree-sorted: wave's 4 rows have ~equal degree
    int s = off[row], e = off[row + 1];
    float a0 = 0, a1 = 0, a2 = 0, a3 = 0, a4 = 0, a5 = 0, a6 = 0, a7 = 0;
    int i = s;
    for (; i + 3 < e; i += 4) {
        int j0 = sl[i], j1 = sl[i + 1], j2 = sl[i + 2], j3 = sl[i + 3];
        uint4 v0 = x[(size_t)j0 * 16 + l16];
        uint4 v1 = x[(size_t)j1 * 16 + l16];
        uint4 v2 = x[(size_t)j2 * 16 + l16];
        uint4 v3 = x[(size_t)j3 * 16 + l16];
        a0 += (bflo(v0.x) + bflo(v1.x)) + (bflo(v2.x) + bflo(v3.x));
        a1 += (bfhi(v0.x) + bfhi(v1.x)) + (bfhi(v2.x) + bfhi(v3.x));
        a2 += (bflo(v0.y) + bflo(v1.y)) + (bflo(v2.y) + bflo(v3.y));
        a3 += (bfhi(v0.y) + bfhi(v1.y)) + (bfhi(v2.y) + bfhi(v3.y));
        a4 += (bflo(v0.z) + bflo(v1.z)) + (bflo(v2.z) + bflo(v3.z));
        a5 += (bfhi(v0.z) + bfhi(v1.z)) + (bfhi(v2.z) + bfhi(v3.z));
        a6 += (bflo(v0.w) + bflo(v1.w)) + (bflo(v2.w) + bflo(v3.w));
        a7 += (bfhi(v0.w) + bfhi(v1.w)) + (bfhi(v2.w) + bfhi(v3.w));
    }
    for (; i < e; ++i) {
        uint4 v = x[(size_t)sl[i] * 16 + l16];
        a0 += bflo(v.x); a1 += bfhi(v.x);
        a2 += bflo(v.y); a3 += bfhi(v.y);
        a4 += bflo(v.z); a5 += bfhi(v.z);
        a6 += bflo(v.w); a7 += bfhi(v.w);
    }
    int d = e - s;
    float inv = 1.f / (float)(d > 0 ? d : 1);
    uint4 r;
    r.x = f2bf(a0 * inv) | (f2bf(a1 * inv) << 16);
    r.y = f2bf(a2 * inv) | (f2bf(a3 * inv) << 16);
    r.z = f2bf(a4 * inv) | (f2bf(a5 * inv) << 16);
    r.w = f2bf(a6 * inv) | (f2bf(a7 * inv) << 16);
    o[(size_t)row * 16 + l16] = r;
}

// ---------------- weight fusion ----------------
__global__ void fuseW(const float* __restrict__ Wn1, const float* __restrict__ Ws1,
                      const float* __restrict__ Wu1,
                      const float* __restrict__ Wn2, const float* __restrict__ Ws2,
                      const float* __restrict__ Wu2, ushort* __restrict__ FT) {
    int j5 = blockIdx.y;
    int l = j5 / 5, t = j5 - l * 5;
    const float* Wn = l ? Wn2 : Wn1;
    const float* Ws = l ? Ws2 : Ws1;
    const float* Wu = l ? Wu2 : Wu1;
    const float *A0, *B0, *A1 = nullptr, *B1 = nullptr;
    float al;
    switch (t) {
        case 0: A0 = Wn;          B0 = Wu;          al = 1.0f; break;
        case 1: A0 = Wn + 16384;  B0 = Wu + 32768;  al = 0.5f; break;
        case 2: A0 = Wn + 32768;  B0 = Wu + 65536;  al = 0.5f; break;
        case 3: A0 = Ws;          B0 = Wu + 16384;  al = 1.0f; break;
        default:
            A0 = Ws + 16384; B0 = Wu + 49152;
            A1 = Ws + 32768; B1 = Wu + 81920;
            al = 0.5f; break;
    }
    int i = blockIdx.x, j = threadIdx.x;
    float s0 = 0, s1 = 0, s2 = 0, s3 = 0;
    #pragma unroll 4
    for (int k = 0; k < 128; k += 4) {
        s0 += A0[i * 128 + k]     * B0[k * 128 + j];
        s1 += A0[i * 128 + k + 1] * B0[(k + 1) * 128 + j];
        s2 += A0[i * 128 + k + 2] * B0[(k + 2) * 128 + j];
        s3 += A0[i * 128 + k + 3] * B0[(k + 3) * 128 + j];
    }
    if (A1) {
        #pragma unroll 4
        for (int k = 0; k < 128; k += 4) {
            s0 += A1[i * 128 + k]     * B1[k * 128 + j];
            s1 += A1[i * 128 + k + 1] * B1[(k + 1) * 128 + j];
            s2 += A1[i * 128 + k + 2] * B1[(k + 2) * 128 + j];
            s3 += A1[i * 128 + k + 3] * B1[(k + 3) * 128 + j];
        }
    }
    float r = al * ((s0 + s1) + (s2 + s3));
    FT[(size_t)j5 * 16384 + j * 128 + i] = (ushort)f2bf(r);
}

__global__ void fuseB(const float* __restrict__ bn1, const float* __restrict__ bs1,
                      const float* __restrict__ bu1, const float* __restrict__ Wu1,
                      const float* __restrict__ bn2, const float* __restrict__ bs2,
                      const float* __restrict__ bu2, const float* __restrict__ Wu2,
                      float* __restrict__ FC) {
    int jb = blockIdx.x;
    int l = jb >> 1, which = jb & 1;
    const float* bn = l ? bn2 : bn1;
    const float* bs = l ? bs2 : bs1;
    const float* bu = l ? bu2 : bu1;
    const float* Wu = l ? Wu2 : Wu1;
    int j = threadIdx.x;
    float s = 0.f;
    if (which == 0) {
        s = bu[j];
        for (int k = 0; k < 128; ++k)
            s += bn[k] * Wu[k * 128 + j] + bs[k] * Wu[(128 + k) * 128 + j];
    } else {
        #pragma unroll
        for (int tt = 1; tt <= 2; ++tt) {
            const float* Wt = Wu + tt * 32768;
            float p = bu[tt * 128 + j];
            for (int k = 0; k < 128; ++k)
                p += bn[tt * 128 + k] * Wt[k * 128 + j] + bs[tt * 128 + k] * Wt[(128 + k) * 128 + j];
            s += 0.5f * p;
        }
    }
    FC[jb * 128 + j] = s;
}

// ---------------- batched MFMA GEMM: double-buffered global_load_lds staging ----------------
// y==0: Cq = Aq0@Wq0 + Aq1@Wq1 + biasq (2 inputs)   y==1: Cp = 3 inputs
// A bf16 [M][128]; W bf16 transposed [n][k]; C bf16; BN col stats -> 32 shadow copies (atomics).
// LDS layout: linear chunk c' of row holds global chunk (c' ^ (row&7)) -- swizzle in SOURCE addr.
__global__ __launch_bounds__(256) void gemm2_mfma(
    const ushort* __restrict__ Aq0, const ushort* __restrict__ Wq0,
    const ushort* __restrict__ Aq1, const ushort* __restrict__ Wq1,
    const ushort* __restrict__ Ap0, const ushort* __restrict__ Wp0,
    const ushort* __restrict__ Ap1, const ushort* __restrict__ Wp1,
    const ushort* __restrict__ Ap2, const ushort* __restrict__ Wp2,
    const float* __restrict__ biasq, const float* __restrict__ biasp,
    ushort* __restrict__ Cq, ushort* __restrict__ Cp, int M,
    float* __restrict__ STW) {
    __shared__ ushort As[2][64 * 128];
    int y = blockIdx.y;
    const float* bias = y ? biasp : biasq;
    ushort* C = y ? Cp : Cq;
    float* colsum = STW + (size_t)(blockIdx.x & 31) * 512 + (y ? 0 : 256);
    float* colsq = colsum + 128;

    int tid = threadIdx.x;
    int wid = tid >> 6;
    int lane = tid & 63;
    int l15 = lane & 15, lg = lane >> 4;
    int row0 = blockIdx.x * 64;
    int nIn = y ? 3 : 2;

    const ushort* Ax[3];
    const ushort* Wx[3];
    Ax[0] = y ? Ap0 : Aq0;  Wx[0] = y ? Wp0 : Wq0;
    Ax[1] = y ? Ap1 : Aq1;  Wx[1] = y ? Wp1 : Wq1;
    Ax[2] = Ap2;            Wx[2] = Wp2;

    // async stage of one 64x128 tile into LDS buffer (source pre-swizzled)
    auto stage = [&](const ushort* A, ushort* buf) {
        #pragma unroll
        for (int p = 0; p < 4; ++p) {
            int row = wid * 16 + p * 4 + (lane >> 4);
            int gr = row0 + row;
            if (gr > M - 1) gr = M - 1;
            const ushort* src = A + (size_t)gr * 128 + (((lane & 15) ^ (row & 7)) * 8);
            gload16(src, buf + (wid * 4 + p) * 512);
        }
    };

    f32x4 acc[4][2];
    #pragma unroll
    for (int rb = 0; rb < 4; ++rb)
        #pragma unroll
        for (int cb = 0; cb < 2; ++cb) acc[rb][cb] = (f32x4){0.f, 0.f, 0.f, 0.f};

    stage(Ax[0], As[0]);
    __syncthreads();                 // drains vmcnt -> As[0] ready
    int cur = 0;

    #pragma unroll
    for (int inp = 0; inp < 3; ++inp) {
        if (inp == 2 && nIn == 2) break;   // wave-uniform
        const ushort* W = Wx[inp];
        // W fragments for this input: issue FIRST (oldest in vmcnt queue)
        short8 bw[4][2];
        #pragma unroll
        for (int k0 = 0; k0 < 4; ++k0)
            #pragma unroll
            for (int cb = 0; cb < 2; ++cb)
                bw[k0][cb] = *(const short8*)(W + (size_t)(wid * 32 + cb * 16 + l15) * 128 + k0 * 32 + lg * 8);
        // prefetch NEXT input's tile into the alternate buffer
        if (inp + 1 < nIn) stage(Ax[inp + 1], As[cur ^ 1]);
        // compute from As[cur]
        #pragma unroll
        for (int k0 = 0; k0 < 4; ++k0) {
            short8 a[4];
            #pragma unroll
            for (int rb = 0; rb < 4; ++rb)
                a[rb] = *(const short8*)&As[cur][(rb * 16 + l15) * 128 + (((k0 * 4 + lg) ^ (l15 & 7)) * 8)];
            #pragma unroll
            for (int rb = 0; rb < 4; ++rb)
                #pragma unroll
                for (int cb = 0; cb < 2; ++cb)
                    acc[rb][cb] = __builtin_amdgcn_mfma_f32_16x16x32_bf16(a[rb], bw[k0][cb], acc[rb][cb], 0, 0, 0);
        }
        __syncthreads();             // all waves done reading As[cur]; prefetch drained
        cur ^= 1;
    }

    float ps[2] = {0.f, 0.f}, pq[2] = {0.f, 0.f};
    int colbase = wid * 32;
    #pragma unroll
    for (int cb = 0; cb < 2; ++cb) {
        int col = colbase + cb * 16 + l15;
        float b = bias[col];
        #pragma unroll
        for (int rb = 0; rb < 4; ++rb) {
            int rbase = row0 + rb * 16 + lg * 4;
            #pragma unroll
            for (int i = 0; i < 4; ++i) {
                int r = rbase + i;
                if (r < M) {
                    float v = acc[rb][cb][i] + b;
                    C[(size_t)r * 128 + col] = (ushort)f2bf(v);
                    ps[cb] += v;
                    pq[cb] += v * v;
                }
            }
        }
    }
    #pragma unroll
    for (int cb = 0; cb < 2; ++cb) {
        ps[cb] += __shfl_xor(ps[cb], 16, 64);
        ps[cb] += __shfl_xor(ps[cb], 32, 64);
        pq[cb] += __shfl_xor(pq[cb], 16, 64);
        pq[cb] += __shfl_xor(pq[cb], 32, 64);
    }
    if (lane < 16) {
        atomicAdd(&colsum[colbase + lane], ps[0]);
        atomicAdd(&colsq[colbase + lane], pq[0]);
        atomicAdd(&colsum[colbase + 16 + lane], ps[1]);
        atomicAdd(&colsq[colbase + 16 + lane], pq[1]);
    }
}

// ---------------- BN finalize: reduce 32 shadow copies, self-zero for next layer ----------------
// ST layout (scale/shift only): [512]=SC0 [640]=SH0 [768]=SC1 [896]=SH1
__global__ void bn_fin2(float* __restrict__ STW, float* __restrict__ ST,
                        const float* __restrict__ g0, const float* __restrict__ b0,
                        const float* __restrict__ g1, const float* __restrict__ b1, int N) {
    int tid = threadIdx.x;
    int which = tid >> 7, c = tid & 127;
    float s = 0.f, q = 0.f;
    #pragma unroll 8
    for (int cp = 0; cp < 32; ++cp) {
        s += STW[(size_t)cp * 512 + which * 256 + c];
        q += STW[(size_t)cp * 512 + which * 256 + 128 + c];
    }
    #pragma unroll 8
    for (int cp = 0; cp < 32; ++cp) {
        STW[(size_t)cp * 512 + which * 256 + c] = 0.f;
        STW[(size_t)cp * 512 + which * 256 + 128 + c] = 0.f;
    }
    const float* g = which ? g1 : g0;
    const float* b = which ? b1 : b0;
    float m = s / (float)N;
    float v = q / (float)N - m * m;
    float rs = rsqrtf(v + 1e-5f);
    float sc = g[c] * rs;
    ST[512 + which * 256 + c] = sc;
    ST[640 + which * 256 + c] = b[c] - m * sc;
}

// ---------------- BN apply + LeakyReLU: bf16 in -> bf16 out, both types (layer 1 only) ----------------
__global__ void bn_apply2(const ushort* __restrict__ Cp, ushort* __restrict__ X0b,
                          const ushort* __restrict__ Cq, ushort* __restrict__ X1b,
                          const float* __restrict__ ST, int n4) {
    int y = blockIdx.y;
    const uint2* in = (const uint2*)(y ? Cq : Cp);
    uint2* out = (uint2*)(y ? X1b : X0b);
    const float* sc = ST + 512 + y * 256;
    const float* sh = sc + 128;
    int i = blockIdx.x * blockDim.x + threadIdx.x;
    int stride = gridDim.x * blockDim.x;
    for (; i < n4; i += stride) {
        uint2 v = in[i];
        int cb = (i * 4) & 127;
        float4 s4 = *(const float4*)&sc[cb];
        float4 h4 = *(const float4*)&sh[cb];
        float y0 = bflo(v.x) * s4.x + h4.x;
        float y1 = bfhi(v.x) * s4.y + h4.y;
        float y2 = bflo(v.y) * s4.z + h4.z;
        float y3 = bfhi(v.y) * s4.w + h4.w;
        y0 = (y0 >= 0.f) ? y0 : 0.01f * y0;
        y1 = (y1 >= 0.f) ? y1 : 0.01f * y1;
        y2 = (y2 >= 0.f) ? y2 : 0.01f * y2;
        y3 = (y3 >= 0.f) ? y3 : 0.01f * y3;
        uint2 o;
        o.x = f2bf(y0) | (f2bf(y1) << 16);
        o.y = f2bf(y2) | (f2bf(y3) << 16);
        out[i] = o;
    }
}

// ---------------- fused BN + LeakyReLU + projection (layer 2), both types ----------------
__global__ void projbn2(const ushort* __restrict__ Cp, const ushort* __restrict__ Cq,
                        const float* __restrict__ ST,
                        const float* __restrict__ Wp, const float* __restrict__ bp,
                        float* __restrict__ out, int N) {
    int y = blockIdx.y;
    const uint* h = (const uint*)(y ? Cq : Cp);
    const float* W = Wp + y * 1024;
    const float* b = bp + y * 8;
    float* op = out + (size_t)y * N * 8;
    __shared__ float Wsh[1024];
    __shared__ float scs[128], shs[128];
    __shared__ float bsh[8];
    int tid = threadIdx.x;
    for (int i = tid; i < 1024; i += 256) Wsh[i] = W[i];
    if (tid < 128) {
        scs[tid] = ST[512 + y * 256 + tid];
        shs[tid] = ST[640 + y * 256 + tid];
    }
    if (tid < 8) bsh[tid] = b[tid];
    __syncthreads();
    int idx = blockIdx.x * 256 + tid;
    if (idx >= N * LBL) return;
    int r = idx >> 3, c = idx & 7;
    const uint* hr = h + (size_t)r * 64;
    float s = bsh[c];
    #pragma unroll
    for (int k2 = 0; k2 < 64; ++k2) {
        uint v = hr[k2];
        float xa = bflo(v) * scs[2 * k2] + shs[2 * k2];
        float xb = bfhi(v) * scs[2 * k2 + 1] + shs[2 * k2 + 1];
        xa = (xa >= 0.f) ? xa : 0.01f * xa;
        xb = (xb >= 0.f) ? xb : 0.01f * xb;
        s += xa * Wsh[(2 * k2) * 8 + c] + xb * Wsh[(2 * k2 + 1) * 8 + c];
    }
    op[idx] = s;
}

// ---------------- host ----------------

extern "C" void kernel_launch(void* const* d_in, const int* in_sizes, int n_in,
                              void* d_out, int out_size, void* d_ws, size_t ws_size,
                              hipStream_t stream) {
    const float* x0 = (const float*)d_in[0];
    const float* x1 = (const float*)d_in[1];
    const float* Wn1 = (const float*)d_in[2];
    const float* Ws1 = (const float*)d_in[3];
    const float* Wu1 = (const float*)d_in[4];
    const float* Wn2 = (const float*)d_in[5];
    const float* Ws2 = (const float*)d_in[6];
    const float* Wu2 = (const float*)d_in[7];
    const float* bnn[2] = {(const float*)d_in[8], (const float*)d_in[11]};
    const float* bss[2] = {(const float*)d_in[9], (const float*)d_in[12]};
    const float* buu[2] = {(const float*)d_in[10], (const float*)d_in[13]};
    const float* gam[2] = {(const float*)d_in[14], (const float*)d_in[16]};
    const float* bet[2] = {(const float*)d_in[15], (const float*)d_in[17]};
    const float* Wp = (const float*)d_in[18];
    const float* bp = (const float*)d_in[19];
    const int* ei[3] = {(const int*)d_in[20], (const int*)d_in[21], (const int*)d_in[22]};

    const int N = in_sizes[0] / 128;
    const int E = in_sizes[20] / 2;
    const int NB = (N + (1 << BSH) - 1) >> BSH;
    float* out = (float*)d_out;

    char* wp_ = (char*)d_ws;
    auto carve = [&](size_t bytes) {
        char* r = wp_;
        wp_ += (bytes + 255) & ~(size_t)255;
        return r;
    };
    size_t nodeB = (size_t)N * 128 * sizeof(ushort);
    ushort* Cp = (ushort*)carve(nodeB);   // h0pre bf16 (pairs aliases this early)
    ushort* Cq = (ushort*)carve(nodeB);   // h1pre bf16
    ushort* Pb = (ushort*)carve(nodeB);
    ushort* Rb = (ushort*)carve(nodeB);
    ushort* Sb = (ushort*)carve(nodeB);
    ushort* X0b = (ushort*)carve(nodeB);
    ushort* X1b = (ushort*)carve(nodeB);
    ushort* x0b = (ushort*)carve(nodeB);
    ushort* x1b = (ushort*)carve(nodeB);
    ushort* FT = (ushort*)carve(10 * 16384 * 2);
    float* FC = (float*)carve(4 * 128 * 4);
    float* ST = (float*)carve(1024 * 4);           // scale/shift region
    float* STW = (float*)carve(32 * 512 * 4);      // 32 shadow BN-stat copies
    int* offs = (int*)carve((size_t)3 * (N + 1) * 4);
    int* srcs = (int*)carve((size_t)3 * E * 4);
    int* perm = (int*)carve((size_t)3 * N * 4);
    int* bcnt = (int*)carve((size_t)3 * NB * 4);
    int* bso = (int*)carve((size_t)3 * (NB + 1) * 4);
    int* gcur = (int*)carve((size_t)3 * NB * 4);
    int* dcnt = (int*)carve((size_t)3 * DBMAX * 4);
    int* dcur = (int*)carve((size_t)3 * DBMAX * 4);
    uint* pairs = (uint*)Cp;  // 3*E*4 = 6 MB <= nodeB (12.8 MB); dead before gemm writes Cp

    const int ag = (N + 15) / 16;
    const int gg = (N + 63) / 64;
    const int pg = (N * LBL + 255) / 256;
    const int bg = (E + 256 * BIN_CH - 1) / (256 * BIN_CH);
    const int dg = (N + 256 * DF_CH - 1) / (256 * DF_CH);

    f2b2<<<dim3(1024, 2), 256, 0, stream>>>((const float4*)x0, (const float4*)x1,
                                            (uint2*)x0b, (uint2*)x1b, N * 32);

    hipMemsetAsync(bcnt, 0, (size_t)3 * NB * 4, stream);
    hipMemsetAsync(dcnt, 0, (size_t)3 * DBMAX * 4, stream);
    hipMemsetAsync(STW, 0, 32 * 512 * 4, stream);
    bhist3<<<dim3(512, 3), 256, 0, stream>>>(ei[0], ei[1], ei[2], E, NB, bcnt);
    bscan<<<1, 64, 0, stream>>>(bcnt, bso, gcur, NB);
    bin3<<<dim3(bg, 3), 256, 0, stream>>>(ei[0], ei[1], ei[2], E, NB, gcur, pairs);
    csr3<<<dim3(NB, 3), 256, 0, stream>>>(pairs, bso, E, N, NB, offs, srcs);

    // degree-sorted row permutation (balances wave trip counts in agg3)
    dhist3<<<dim3(64, 3), 256, 0, stream>>>(offs, dcnt, N);
    dscan<<<1, 64, 0, stream>>>(dcnt, dcur);
    dfill3<<<dim3(dg, 3), 256, 0, stream>>>(offs, dcur, perm, N);

    fuseW<<<dim3(128, 10), 128, 0, stream>>>(Wn1, Ws1, Wu1, Wn2, Ws2, Wu2, FT);
    fuseB<<<4, 128, 0, stream>>>(bnn[0], bss[0], buu[0], Wu1, bnn[1], bss[1], buu[1], Wu2, FC);

    const ushort* srcS[2][3] = {{x0b, x1b, x0b}, {X0b, X1b, X0b}};
    const ushort* dstX[2][2] = {{x0b, x1b}, {X0b, X1b}};

    for (int l = 0; l < 2; ++l) {
        const ushort* FA0T = FT + (size_t)(l * 5 + 0) * 16384;
        const ushort* FA1T = FT + (size_t)(l * 5 + 1) * 16384;
        const ushort* FA2T = FT + (size_t)(l * 5 + 2) * 16384;
        const ushort* FB1T = FT + (size_t)(l * 5 + 3) * 16384;
        const ushort* FB0T = FT + (size_t)(l * 5 + 4) * 16384;
        const float* fcH1 = FC + (l * 2 + 0) * 128;
        const float* fcH0 = FC + (l * 2 + 1) * 128;

        agg3<<<dim3(ag, 3), 256, 0, stream>>>(srcS[l][0], srcS[l][1], srcS[l][2],
                                              (uint*)Pb, (uint*)Rb, (uint*)Sb,
                                              offs, srcs, perm, N, E);

        // y=0: Cq = Pb@FA0 + x1@FB1 ; y=1: Cp = Rb@FA1 + Sb@FA2 + x0@FB0
        gemm2_mfma<<<dim3(gg, 2), 256, 0, stream>>>(
            Pb, FA0T, dstX[l][1], FB1T,
            Rb, FA1T, Sb, FA2T, dstX[l][0], FB0T,
            fcH1, fcH0, Cq, Cp, N, STW);

        bn_fin2<<<1, 256, 0, stream>>>(STW, ST, gam[l], bet[l], gam[l] + 128, bet[l] + 128, N);
        if (l == 0)
            bn_apply2<<<dim3(1024, 2), 256, 0, stream>>>(Cp, X0b, Cq, X1b, ST, N * 32);
    }

    // layer-2 BN + LeakyReLU fused into the projection
    projbn2<<<dim3(pg, 2), 256, 0, stream>>>(Cp, Cq, ST, Wp, bp, out, N);
}

// Round 12
// 316.755 us; speedup vs baseline: 1.0280x; 1.0280x over previous
//
#include <hip/hip_runtime.h>

#define LBL 8
#define NBMAX 128
#define BSH 9            // 512 dsts per bucket
#define BCAP 8192        // LDS sort capacity per bucket (mean ~5100)
#define DBMAX 64         // degree-sort buckets
#define WIN 1024         // local degree-sort window

typedef __attribute__((ext_vector_type(8))) short short8;
typedef __attribute__((ext_vector_type(4))) float f32x4;

__device__ __forceinline__ uint f2bf(float x) {
    uint u = __float_as_uint(x);
    return (u + 0x7fffu + ((u >> 16) & 1u)) >> 16;
}
__device__ __forceinline__ float bflo(uint v) { return __uint_as_float(v << 16); }
__device__ __forceinline__ float bfhi(uint v) { return __uint_as_float(v & 0xffff0000u); }

// async global->LDS 16B per lane: dest = lds_base(wave-uniform) + lane*16
__device__ __forceinline__ void gload16(const ushort* g, ushort* l) {
    __builtin_amdgcn_global_load_lds((const __attribute__((address_space(1))) uint*)g,
                                     (__attribute__((address_space(3))) uint*)l, 16, 0, 0);
}

// ---------------- fp32 -> bf16 conversion (both node types, one dispatch) ----------------
__global__ void f2b2(const float4* __restrict__ x0, const float4* __restrict__ x1,
                     uint2* __restrict__ o0, uint2* __restrict__ o1, int n4) {
    int y = blockIdx.y;
    const float4* in = y ? x1 : x0;
    uint2* out = y ? o1 : o0;
    int i = blockIdx.x * blockDim.x + threadIdx.x;
    int stride = gridDim.x * blockDim.x;
    for (; i < n4; i += stride) {
        float4 v = in[i];
        uint2 o;
        o.x = f2bf(v.x) | (f2bf(v.y) << 16);
        o.y = f2bf(v.z) | (f2bf(v.w) << 16);
        out[i] = o;
    }
}

// ---------------- CSR build via two-pass counting sort (packed 4B records) ----------------

__global__ void bhist3(const int* __restrict__ e0, const int* __restrict__ e1,
                       const int* __restrict__ e2, int E, int NB, int* __restrict__ bcnt) {
    int m = blockIdx.y;
    const int* dst = (m == 0 ? e0 : (m == 1 ? e1 : e2)) + E;
    __shared__ int h[NBMAX];
    int tid = threadIdx.x;
    if (tid < NB) h[tid] = 0;
    __syncthreads();
    int i = blockIdx.x * blockDim.x + tid, st = gridDim.x * blockDim.x;
    for (; i < E; i += st) atomicAdd(&h[dst[i] >> BSH], 1);
    __syncthreads();
    if (tid < NB && h[tid]) atomicAdd(&bcnt[m * NB + tid], h[tid]);
}

__global__ void bscan(const int* __restrict__ bcnt, int* __restrict__ bso,
                      int* __restrict__ gcur, int NB) {
    int m = threadIdx.x;
    if (m >= 3) return;
    int acc = 0;
    for (int b = 0; b < NB; ++b) {
        bso[m * (NB + 1) + b] = acc;
        gcur[m * NB + b] = acc;
        acc += bcnt[m * NB + b];
    }
    bso[m * (NB + 1) + NB] = acc;
}

// record: src (16b) | dst-low-9 << 16   (requires N <= 65536)
#define BIN_CH 16
__global__ __launch_bounds__(256) void bin3(const int* __restrict__ e0, const int* __restrict__ e1,
                                            const int* __restrict__ e2, int E, int NB,
                                            int* __restrict__ gcur, uint* __restrict__ pairs) {
    int m = blockIdx.y;
    const int* eb = (m == 0 ? e0 : (m == 1 ? e1 : e2));
    const int* src = eb;
    const int* dst = eb + E;
    uint* pp = pairs + (size_t)m * E;
    int* gc = gcur + m * NB;
    __shared__ int h[NBMAX], base[NBMAX], pos[NBMAX];
    int tid = threadIdx.x;
    if (tid < NB) { h[tid] = 0; pos[tid] = 0; }
    __syncthreads();
    int i0 = blockIdx.x * (256 * BIN_CH);
    uint pk[BIN_CH];
    int bk[BIN_CH];
    #pragma unroll
    for (int u = 0; u < BIN_CH; ++u) {
        int i = i0 + u * 256 + tid;
        bk[u] = -1;
        if (i < E) {
            int s = src[i], d = dst[i];
            bk[u] = d >> BSH;
            pk[u] = (uint)s | ((uint)(d & ((1 << BSH) - 1)) << 16);
            atomicAdd(&h[bk[u]], 1);
        }
    }
    __syncthreads();
    if (tid < NB && h[tid]) base[tid] = atomicAdd(&gc[tid], h[tid]);
    __syncthreads();
    #pragma unroll
    for (int u = 0; u < BIN_CH; ++u) {
        if (bk[u] >= 0) {
            int p = base[bk[u]] + atomicAdd(&pos[bk[u]], 1);
            pp[p] = pk[u];
        }
    }
}

__global__ __launch_bounds__(256) void csr3(const uint* __restrict__ pairs, const int* __restrict__ bso,
                                            int E, int N, int NB,
                                            int* __restrict__ offs, ushort* __restrict__ srcs) {
    int m = blockIdx.y, b = blockIdx.x;
    const uint* pp = pairs + (size_t)m * E;
    int gstart = bso[m * (NB + 1) + b];
    int gend = bso[m * (NB + 1) + b + 1];
    int cnt = gend - gstart;
    if (cnt > BCAP) cnt = BCAP;
    int d0 = b << BSH;
    int dcnt = N - d0;
    if (dcnt > (1 << BSH)) dcnt = 1 << BSH;

    __shared__ int hist[1 << BSH], po[1 << BSH], off0[1 << BSH];
    __shared__ int lsort[BCAP];
    __shared__ int wsum[4];
    int tid = threadIdx.x;
    hist[tid] = 0;
    hist[tid + 256] = 0;
    __syncthreads();
    for (int i = tid; i < cnt; i += 256) atomicAdd(&hist[pp[gstart + i] >> 16], 1);
    __syncthreads();
    int a = hist[2 * tid], b2 = hist[2 * tid + 1];
    int s = a + b2;
    int lane = tid & 63, w = tid >> 6;
    #pragma unroll
    for (int o = 1; o < 64; o <<= 1) {
        int v = __shfl_up(s, o, 64);
        if (lane >= o) s += v;
    }
    if (lane == 63) wsum[w] = s;
    __syncthreads();
    int wp = 0;
    #pragma unroll
    for (int q = 0; q < 4; ++q)
        if (q < w) wp += wsum[q];
    int excl = wp + s - a - b2;
    off0[2 * tid] = excl; off0[2 * tid + 1] = excl + a;
    po[2 * tid] = excl;   po[2 * tid + 1] = excl + a;
    __syncthreads();
    for (int j = tid; j < dcnt; j += 256) offs[(size_t)m * (N + 1) + d0 + j] = gstart + off0[j];
    if (b == NB - 1 && tid == 0) offs[(size_t)m * (N + 1) + N] = bso[m * (NB + 1) + NB];
    for (int i = tid; i < cnt; i += 256) {
        uint e = pp[gstart + i];
        int p = atomicAdd(&po[e >> 16], 1);
        if (p < BCAP) lsort[p] = (int)(e & 0xffffu);
    }
    __syncthreads();
    for (int i = tid; i < cnt; i += 256) srcs[(size_t)m * E + gstart + i] = (ushort)lsort[i];
}

// ---------------- window-local degree sort: balances wave trip counts, keeps locality ----------------
__global__ __launch_bounds__(256) void wsort3(const int* __restrict__ offs,
                                              int* __restrict__ perm, int N) {
    int m = blockIdx.y;
    const int* off = offs + (size_t)m * (N + 1);
    int* pm = perm + (size_t)m * N;
    int w0 = blockIdx.x * WIN;
    int cnt = N - w0;
    if (cnt > WIN) cnt = WIN;
    __shared__ int h[DBMAX];
    __shared__ int base[DBMAX];
    __shared__ ushort deg[WIN];
    int tid = threadIdx.x;
    if (tid < DBMAX) h[tid] = 0;
    __syncthreads();
    for (int i = tid; i < cnt; i += 256) {
        int d = off[w0 + i + 1] - off[w0 + i];
        if (d >= DBMAX) d = DBMAX - 1;
        deg[i] = (ushort)d;
        atomicAdd(&h[d], 1);
    }
    __syncthreads();
    if (tid < 64) {                    // wave-0 exclusive scan of 64 buckets
        int v = h[tid];
        int s = v;
        #pragma unroll
        for (int o = 1; o < 64; o <<= 1) {
            int t = __shfl_up(s, o, 64);
            if (tid >= o) s += t;
        }
        base[tid] = s - v;
    }
    __syncthreads();
    for (int i = tid; i < cnt; i += 256) {
        int p = atomicAdd(&base[deg[i]], 1);
        pm[w0 + p] = w0 + i;
    }
}

// ---------------- segment mean: 4 rows/wave via window-sorted perm ----------------
__global__ void agg3(const ushort* __restrict__ s0, const ushort* __restrict__ s1,
                     const ushort* __restrict__ s2,
                     uint* __restrict__ o0, uint* __restrict__ o1, uint* __restrict__ o2,
                     const int* __restrict__ offs, const ushort* __restrict__ srcs,
                     const int* __restrict__ perm, int n, int E) {
    int m = blockIdx.y;
    const uint4* x = (const uint4*)(m == 0 ? s0 : (m == 1 ? s1 : s2));
    uint4* o = (uint4*)(m == 0 ? o0 : (m == 1 ? o1 : o2));
    const int* off = offs + (size_t)m * (n + 1);
    const ushort* sl = srcs + (size_t)m * E;
    const int* pm = perm + (size_t)m * n;

    int tid = threadIdx.x;
    int l16 = tid & 15;
    int gid = blockIdx.x * 16 + (tid >> 4);
    if (gid >= n) return;
    int row = pm[gid];                 // window-sorted: wave's 4 rows have ~equal degree
    int s = off[row], e = off[row + 1];
    float a0 = 0, a1 = 0, a2 = 0, a3 = 0, a4 = 0, a5 = 0, a6 = 0, a7 = 0;
    int i = s;
    for (; i + 3 < e; i += 4) {
        int j0 = sl[i], j1 = sl[i + 1], j2 = sl[i + 2], j3 = sl[i + 3];
        uint4 v0 = x[(size_t)j0 * 16 + l16];
        uint4 v1 = x[(size_t)j1 * 16 + l16];
        uint4 v2 = x[(size_t)j2 * 16 + l16];
        uint4 v3 = x[(size_t)j3 * 16 + l16];
        a0 += (bflo(v0.x) + bflo(v1.x)) + (bflo(v2.x) + bflo(v3.x));
        a1 += (bfhi(v0.x) + bfhi(v1.x)) + (bfhi(v2.x) + bfhi(v3.x));
        a2 += (bflo(v0.y) + bflo(v1.y)) + (bflo(v2.y) + bflo(v3.y));
        a3 += (bfhi(v0.y) + bfhi(v1.y)) + (bfhi(v2.y) + bfhi(v3.y));
        a4 += (bflo(v0.z) + bflo(v1.z)) + (bflo(v2.z) + bflo(v3.z));
        a5 += (bfhi(v0.z) + bfhi(v1.z)) + (bfhi(v2.z) + bfhi(v3.z));
        a6 += (bflo(v0.w) + bflo(v1.w)) + (bflo(v2.w) + bflo(v3.w));
        a7 += (bfhi(v0.w) + bfhi(v1.w)) + (bfhi(v2.w) + bfhi(v3.w));
    }
    for (; i < e; ++i) {
        uint4 v = x[(size_t)sl[i] * 16 + l16];
        a0 += bflo(v.x); a1 += bfhi(v.x);
        a2 += bflo(v.y); a3 += bfhi(v.y);
        a4 += bflo(v.z); a5 += bfhi(v.z);
        a6 += bflo(v.w); a7 += bfhi(v.w);
    }
    int d = e - s;
    float inv = 1.f / (float)(d > 0 ? d : 1);
    uint4 r;
    r.x = f2bf(a0 * inv) | (f2bf(a1 * inv) << 16);
    r.y = f2bf(a2 * inv) | (f2bf(a3 * inv) << 16);
    r.z = f2bf(a4 * inv) | (f2bf(a5 * inv) << 16);
    r.w = f2bf(a6 * inv) | (f2bf(a7 * inv) << 16);
    o[(size_t)row * 16 + l16] = r;
}

// ---------------- weight fusion ----------------
__global__ void fuseW(const float* __restrict__ Wn1, const float* __restrict__ Ws1,
                      const float* __restrict__ Wu1,
                      const float* __restrict__ Wn2, const float* __restrict__ Ws2,
                      const float* __restrict__ Wu2, ushort* __restrict__ FT) {
    int j5 = blockIdx.y;
    int l = j5 / 5, t = j5 - l * 5;
    const float* Wn = l ? Wn2 : Wn1;
    const float* Ws = l ? Ws2 : Ws1;
    const float* Wu = l ? Wu2 : Wu1;
    const float *A0, *B0, *A1 = nullptr, *B1 = nullptr;
    float al;
    switch (t) {
        case 0: A0 = Wn;          B0 = Wu;          al = 1.0f; break;
        case 1: A0 = Wn + 16384;  B0 = Wu + 32768;  al = 0.5f; break;
        case 2: A0 = Wn + 32768;  B0 = Wu + 65536;  al = 0.5f; break;
        case 3: A0 = Ws;          B0 = Wu + 16384;  al = 1.0f; break;
        default:
            A0 = Ws + 16384; B0 = Wu + 49152;
            A1 = Ws + 32768; B1 = Wu + 81920;
            al = 0.5f; break;
    }
    int i = blockIdx.x, j = threadIdx.x;
    float s0 = 0, s1 = 0, s2 = 0, s3 = 0;
    #pragma unroll 4
    for (int k = 0; k < 128; k += 4) {
        s0 += A0[i * 128 + k]     * B0[k * 128 + j];
        s1 += A0[i * 128 + k + 1] * B0[(k + 1) * 128 + j];
        s2 += A0[i * 128 + k + 2] * B0[(k + 2) * 128 + j];
        s3 += A0[i * 128 + k + 3] * B0[(k + 3) * 128 + j];
    }
    if (A1) {
        #pragma unroll 4
        for (int k = 0; k < 128; k += 4) {
            s0 += A1[i * 128 + k]     * B1[k * 128 + j];
            s1 += A1[i * 128 + k + 1] * B1[(k + 1) * 128 + j];
            s2 += A1[i * 128 + k + 2] * B1[(k + 2) * 128 + j];
            s3 += A1[i * 128 + k + 3] * B1[(k + 3) * 128 + j];
        }
    }
    float r = al * ((s0 + s1) + (s2 + s3));
    FT[(size_t)j5 * 16384 + j * 128 + i] = (ushort)f2bf(r);
}

__global__ void fuseB(const float* __restrict__ bn1, const float* __restrict__ bs1,
                      const float* __restrict__ bu1, const float* __restrict__ Wu1,
                      const float* __restrict__ bn2, const float* __restrict__ bs2,
                      const float* __restrict__ bu2, const float* __restrict__ Wu2,
                      float* __restrict__ FC) {
    int jb = blockIdx.x;
    int l = jb >> 1, which = jb & 1;
    const float* bn = l ? bn2 : bn1;
    const float* bs = l ? bs2 : bs1;
    const float* bu = l ? bu2 : bu1;
    const float* Wu = l ? Wu2 : Wu1;
    int j = threadIdx.x;
    float s = 0.f;
    if (which == 0) {
        s = bu[j];
        for (int k = 0; k < 128; ++k)
            s += bn[k] * Wu[k * 128 + j] + bs[k] * Wu[(128 + k) * 128 + j];
    } else {
        #pragma unroll
        for (int tt = 1; tt <= 2; ++tt) {
            const float* Wt = Wu + tt * 32768;
            float p = bu[tt * 128 + j];
            for (int k = 0; k < 128; ++k)
                p += bn[tt * 128 + k] * Wt[k * 128 + j] + bs[tt * 128 + k] * Wt[(128 + k) * 128 + j];
            s += 0.5f * p;
        }
    }
    FC[jb * 128 + j] = s;
}

// ---------------- batched MFMA GEMM: double-buffered global_load_lds staging ----------------
__global__ __launch_bounds__(256) void gemm2_mfma(
    const ushort* __restrict__ Aq0, const ushort* __restrict__ Wq0,
    const ushort* __restrict__ Aq1, const ushort* __restrict__ Wq1,
    const ushort* __restrict__ Ap0, const ushort* __restrict__ Wp0,
    const ushort* __restrict__ Ap1, const ushort* __restrict__ Wp1,
    const ushort* __restrict__ Ap2, const ushort* __restrict__ Wp2,
    const float* __restrict__ biasq, const float* __restrict__ biasp,
    ushort* __restrict__ Cq, ushort* __restrict__ Cp, int M,
    float* __restrict__ STW) {
    __shared__ ushort As[2][64 * 128];
    int y = blockIdx.y;
    const float* bias = y ? biasp : biasq;
    ushort* C = y ? Cp : Cq;
    float* colsum = STW + (size_t)(blockIdx.x & 31) * 512 + (y ? 0 : 256);
    float* colsq = colsum + 128;

    int tid = threadIdx.x;
    int wid = tid >> 6;
    int lane = tid & 63;
    int l15 = lane & 15, lg = lane >> 4;
    int row0 = blockIdx.x * 64;
    int nIn = y ? 3 : 2;

    const ushort* Ax[3];
    const ushort* Wx[3];
    Ax[0] = y ? Ap0 : Aq0;  Wx[0] = y ? Wp0 : Wq0;
    Ax[1] = y ? Ap1 : Aq1;  Wx[1] = y ? Wp1 : Wq1;
    Ax[2] = Ap2;            Wx[2] = Wp2;

    auto stage = [&](const ushort* A, ushort* buf) {
        #pragma unroll
        for (int p = 0; p < 4; ++p) {
            int row = wid * 16 + p * 4 + (lane >> 4);
            int gr = row0 + row;
            if (gr > M - 1) gr = M - 1;
            const ushort* src = A + (size_t)gr * 128 + (((lane & 15) ^ (row & 7)) * 8);
            gload16(src, buf + (wid * 4 + p) * 512);
        }
    };

    f32x4 acc[4][2];
    #pragma unroll
    for (int rb = 0; rb < 4; ++rb)
        #pragma unroll
        for (int cb = 0; cb < 2; ++cb) acc[rb][cb] = (f32x4){0.f, 0.f, 0.f, 0.f};

    stage(Ax[0], As[0]);
    __syncthreads();
    int cur = 0;

    #pragma unroll
    for (int inp = 0; inp < 3; ++inp) {
        if (inp == 2 && nIn == 2) break;   // wave-uniform
        const ushort* W = Wx[inp];
        short8 bw[4][2];
        #pragma unroll
        for (int k0 = 0; k0 < 4; ++k0)
            #pragma unroll
            for (int cb = 0; cb < 2; ++cb)
                bw[k0][cb] = *(const short8*)(W + (size_t)(wid * 32 + cb * 16 + l15) * 128 + k0 * 32 + lg * 8);
        if (inp + 1 < nIn) stage(Ax[inp + 1], As[cur ^ 1]);
        #pragma unroll
        for (int k0 = 0; k0 < 4; ++k0) {
            short8 a[4];
            #pragma unroll
            for (int rb = 0; rb < 4; ++rb)
                a[rb] = *(const short8*)&As[cur][(rb * 16 + l15) * 128 + (((k0 * 4 + lg) ^ (l15 & 7)) * 8)];
            #pragma unroll
            for (int rb = 0; rb < 4; ++rb)
                #pragma unroll
                for (int cb = 0; cb < 2; ++cb)
                    acc[rb][cb] = __builtin_amdgcn_mfma_f32_16x16x32_bf16(a[rb], bw[k0][cb], acc[rb][cb], 0, 0, 0);
        }
        __syncthreads();
        cur ^= 1;
    }

    float ps[2] = {0.f, 0.f}, pq[2] = {0.f, 0.f};
    int colbase = wid * 32;
    #pragma unroll
    for (int cb = 0; cb < 2; ++cb) {
        int col = colbase + cb * 16 + l15;
        float b = bias[col];
        #pragma unroll
        for (int rb = 0; rb < 4; ++rb) {
            int rbase = row0 + rb * 16 + lg * 4;
            #pragma unroll
            for (int i = 0; i < 4; ++i) {
                int r = rbase + i;
                if (r < M) {
                    float v = acc[rb][cb][i] + b;
                    C[(size_t)r * 128 + col] = (ushort)f2bf(v);
                    ps[cb] += v;
                    pq[cb] += v * v;
                }
            }
        }
    }
    #pragma unroll
    for (int cb = 0; cb < 2; ++cb) {
        ps[cb] += __shfl_xor(ps[cb], 16, 64);
        ps[cb] += __shfl_xor(ps[cb], 32, 64);
        pq[cb] += __shfl_xor(pq[cb], 16, 64);
        pq[cb] += __shfl_xor(pq[cb], 32, 64);
    }
    if (lane < 16) {
        atomicAdd(&colsum[colbase + lane], ps[0]);
        atomicAdd(&colsq[colbase + lane], pq[0]);
        atomicAdd(&colsum[colbase + 16 + lane], ps[1]);
        atomicAdd(&colsq[colbase + 16 + lane], pq[1]);
    }
}

// ---------------- BN finalize: reduce 32 shadow copies, self-zero for next layer ----------------
__global__ void bn_fin2(float* __restrict__ STW, float* __restrict__ ST,
                        const float* __restrict__ g0, const float* __restrict__ b0,
                        const float* __restrict__ g1, const float* __restrict__ b1, int N) {
    int tid = threadIdx.x;
    int which = tid >> 7, c = tid & 127;
    float s = 0.f, q = 0.f;
    #pragma unroll 8
    for (int cp = 0; cp < 32; ++cp) {
        s += STW[(size_t)cp * 512 + which * 256 + c];
        q += STW[(size_t)cp * 512 + which * 256 + 128 + c];
    }
    #pragma unroll 8
    for (int cp = 0; cp < 32; ++cp) {
        STW[(size_t)cp * 512 + which * 256 + c] = 0.f;
        STW[(size_t)cp * 512 + which * 256 + 128 + c] = 0.f;
    }
    const float* g = which ? g1 : g0;
    const float* b = which ? b1 : b0;
    float m = s / (float)N;
    float v = q / (float)N - m * m;
    float rs = rsqrtf(v + 1e-5f);
    float sc = g[c] * rs;
    ST[512 + which * 256 + c] = sc;
    ST[640 + which * 256 + c] = b[c] - m * sc;
}

// ---------------- BN apply + LeakyReLU: bf16 in -> bf16 out (layer 1 only) ----------------
__global__ void bn_apply2(const ushort* __restrict__ Cp, ushort* __restrict__ X0b,
                          const ushort* __restrict__ Cq, ushort* __restrict__ X1b,
                          const float* __restrict__ ST, int n4) {
    int y = blockIdx.y;
    const uint2* in = (const uint2*)(y ? Cq : Cp);
    uint2* out = (uint2*)(y ? X1b : X0b);
    const float* sc = ST + 512 + y * 256;
    const float* sh = sc + 128;
    int i = blockIdx.x * blockDim.x + threadIdx.x;
    int stride = gridDim.x * blockDim.x;
    for (; i < n4; i += stride) {
        uint2 v = in[i];
        int cb = (i * 4) & 127;
        float4 s4 = *(const float4*)&sc[cb];
        float4 h4 = *(const float4*)&sh[cb];
        float y0 = bflo(v.x) * s4.x + h4.x;
        float y1 = bfhi(v.x) * s4.y + h4.y;
        float y2 = bflo(v.y) * s4.z + h4.z;
        float y3 = bfhi(v.y) * s4.w + h4.w;
        y0 = (y0 >= 0.f) ? y0 : 0.01f * y0;
        y1 = (y1 >= 0.f) ? y1 : 0.01f * y1;
        y2 = (y2 >= 0.f) ? y2 : 0.01f * y2;
        y3 = (y3 >= 0.f) ? y3 : 0.01f * y3;
        uint2 o;
        o.x = f2bf(y0) | (f2bf(y1) << 16);
        o.y = f2bf(y2) | (f2bf(y3) << 16);
        out[i] = o;
    }
}

// ---------------- fused BN + LeakyReLU + projection (layer 2), both types ----------------
__global__ void projbn2(const ushort* __restrict__ Cp, const ushort* __restrict__ Cq,
                        const float* __restrict__ ST,
                        const float* __restrict__ Wp, const float* __restrict__ bp,
                        float* __restrict__ out, int N) {
    int y = blockIdx.y;
    const uint* h = (const uint*)(y ? Cq : Cp);
    const float* W = Wp + y * 1024;
    const float* b = bp + y * 8;
    float* op = out + (size_t)y * N * 8;
    __shared__ float Wsh[1024];
    __shared__ float scs[128], shs[128];
    __shared__ float bsh[8];
    int tid = threadIdx.x;
    for (int i = tid; i < 1024; i += 256) Wsh[i] = W[i];
    if (tid < 128) {
        scs[tid] = ST[512 + y * 256 + tid];
        shs[tid] = ST[640 + y * 256 + tid];
    }
    if (tid < 8) bsh[tid] = b[tid];
    __syncthreads();
    int idx = blockIdx.x * 256 + tid;
    if (idx >= N * LBL) return;
    int r = idx >> 3, c = idx & 7;
    const uint* hr = h + (size_t)r * 64;
    float s = bsh[c];
    #pragma unroll
    for (int k2 = 0; k2 < 64; ++k2) {
        uint v = hr[k2];
        float xa = bflo(v) * scs[2 * k2] + shs[2 * k2];
        float xb = bfhi(v) * scs[2 * k2 + 1] + shs[2 * k2 + 1];
        xa = (xa >= 0.f) ? xa : 0.01f * xa;
        xb = (xb >= 0.f) ? xb : 0.01f * xb;
        s += xa * Wsh[(2 * k2) * 8 + c] + xb * Wsh[(2 * k2 + 1) * 8 + c];
    }
    op[idx] = s;
}

// ---------------- host ----------------

extern "C" void kernel_launch(void* const* d_in, const int* in_sizes, int n_in,
                              void* d_out, int out_size, void* d_ws, size_t ws_size,
                              hipStream_t stream) {
    const float* x0 = (const float*)d_in[0];
    const float* x1 = (const float*)d_in[1];
    const float* Wn1 = (const float*)d_in[2];
    const float* Ws1 = (const float*)d_in[3];
    const float* Wu1 = (const float*)d_in[4];
    const float* Wn2 = (const float*)d_in[5];
    const float* Ws2 = (const float*)d_in[6];
    const float* Wu2 = (const float*)d_in[7];
    const float* bnn[2] = {(const float*)d_in[8], (const float*)d_in[11]};
    const float* bss[2] = {(const float*)d_in[9], (const float*)d_in[12]};
    const float* buu[2] = {(const float*)d_in[10], (const float*)d_in[13]};
    const float* gam[2] = {(const float*)d_in[14], (const float*)d_in[16]};
    const float* bet[2] = {(const float*)d_in[15], (const float*)d_in[17]};
    const float* Wp = (const float*)d_in[18];
    const float* bp = (const float*)d_in[19];
    const int* ei[3] = {(const int*)d_in[20], (const int*)d_in[21], (const int*)d_in[22]};

    const int N = in_sizes[0] / 128;
    const int E = in_sizes[20] / 2;
    const int NB = (N + (1 << BSH) - 1) >> BSH;
    float* out = (float*)d_out;

    char* wp_ = (char*)d_ws;
    auto carve = [&](size_t bytes) {
        char* r = wp_;
        wp_ += (bytes + 255) & ~(size_t)255;
        return r;
    };
    size_t nodeB = (size_t)N * 128 * sizeof(ushort);
    ushort* Cp = (ushort*)carve(nodeB);   // h0pre bf16 (pairs aliases this early)
    ushort* Cq = (ushort*)carve(nodeB);   // h1pre bf16
    ushort* Pb = (ushort*)carve(nodeB);
    ushort* Rb = (ushort*)carve(nodeB);
    ushort* Sb = (ushort*)carve(nodeB);
    ushort* X0b = (ushort*)carve(nodeB);
    ushort* X1b = (ushort*)carve(nodeB);
    ushort* x0b = (ushort*)carve(nodeB);
    ushort* x1b = (ushort*)carve(nodeB);
    ushort* FT = (ushort*)carve(10 * 16384 * 2);
    float* FC = (float*)carve(4 * 128 * 4);
    float* ST = (float*)carve(1024 * 4);           // scale/shift region
    float* STW = (float*)carve(32 * 512 * 4);      // 32 shadow BN-stat copies
    int* offs = (int*)carve((size_t)3 * (N + 1) * 4);
    ushort* srcs = (ushort*)carve((size_t)3 * E * 2);
    int* perm = (int*)carve((size_t)3 * N * 4);
    int* bcnt = (int*)carve((size_t)3 * NB * 4);
    int* bso = (int*)carve((size_t)3 * (NB + 1) * 4);
    int* gcur = (int*)carve((size_t)3 * NB * 4);
    uint* pairs = (uint*)Cp;  // 3*E*4 = 6 MB <= nodeB (12.8 MB); dead before gemm writes Cp

    const int ag = (N + 15) / 16;
    const int gg = (N + 63) / 64;
    const int pg = (N * LBL + 255) / 256;
    const int bg = (E + 256 * BIN_CH - 1) / (256 * BIN_CH);
    const int wg = (N + WIN - 1) / WIN;

    f2b2<<<dim3(1024, 2), 256, 0, stream>>>((const float4*)x0, (const float4*)x1,
                                            (uint2*)x0b, (uint2*)x1b, N * 32);

    hipMemsetAsync(bcnt, 0, (size_t)3 * NB * 4, stream);
    hipMemsetAsync(STW, 0, 32 * 512 * 4, stream);
    bhist3<<<dim3(512, 3), 256, 0, stream>>>(ei[0], ei[1], ei[2], E, NB, bcnt);
    bscan<<<1, 64, 0, stream>>>(bcnt, bso, gcur, NB);
    bin3<<<dim3(bg, 3), 256, 0, stream>>>(ei[0], ei[1], ei[2], E, NB, gcur, pairs);
    csr3<<<dim3(NB, 3), 256, 0, stream>>>(pairs, bso, E, N, NB, offs, srcs);

    // window-local degree sort (balances wave trip counts, keeps offs/write locality)
    wsort3<<<dim3(wg, 3), 256, 0, stream>>>(offs, perm, N);

    fuseW<<<dim3(128, 10), 128, 0, stream>>>(Wn1, Ws1, Wu1, Wn2, Ws2, Wu2, FT);
    fuseB<<<4, 128, 0, stream>>>(bnn[0], bss[0], buu[0], Wu1, bnn[1], bss[1], buu[1], Wu2, FC);

    const ushort* srcS[2][3] = {{x0b, x1b, x0b}, {X0b, X1b, X0b}};
    const ushort* dstX[2][2] = {{x0b, x1b}, {X0b, X1b}};

    for (int l = 0; l < 2; ++l) {
        const ushort* FA0T = FT + (size_t)(l * 5 + 0) * 16384;
        const ushort* FA1T = FT + (size_t)(l * 5 + 1) * 16384;
        const ushort* FA2T = FT + (size_t)(l * 5 + 2) * 16384;
        const ushort* FB1T = FT + (size_t)(l * 5 + 3) * 16384;
        const ushort* FB0T = FT + (size_t)(l * 5 + 4) * 16384;
        const float* fcH1 = FC + (l * 2 + 0) * 128;
        const float* fcH0 = FC + (l * 2 + 1) * 128;

        agg3<<<dim3(ag, 3), 256, 0, stream>>>(srcS[l][0], srcS[l][1], srcS[l][2],
                                              (uint*)Pb, (uint*)Rb, (uint*)Sb,
                                              offs, srcs, perm, N, E);

        // y=0: Cq = Pb@FA0 + x1@FB1 ; y=1: Cp = Rb@FA1 + Sb@FA2 + x0@FB0
        gemm2_mfma<<<dim3(gg, 2), 256, 0, stream>>>(
            Pb, FA0T, dstX[l][1], FB1T,
            Rb, FA1T, Sb, FA2T, dstX[l][0], FB0T,
            fcH1, fcH0, Cq, Cp, N, STW);

        bn_fin2<<<1, 256, 0, stream>>>(STW, ST, gam[l], bet[l], gam[l] + 128, bet[l] + 128, N);
        if (l == 0)
            bn_apply2<<<dim3(1024, 2), 256, 0, stream>>>(Cp, X0b, Cq, X1b, ST, N * 32);
    }

    // layer-2 BN + LeakyReLU fused into the projection
    projbn2<<<dim3(pg, 2), 256, 0, stream>>>(Cp, Cq, ST, Wp, bp, out, N);
}

// Round 13
// 308.366 us; speedup vs baseline: 1.0560x; 1.0272x over previous
//
#include <hip/hip_runtime.h>

#define LBL 8
#define NBMAX 128
#define BSH 9            // 512 dsts per bucket
#define BCAP 8192        // LDS sort capacity per bucket (mean ~5100)

typedef __attribute__((ext_vector_type(8))) short short8;
typedef __attribute__((ext_vector_type(4))) float f32x4;

__device__ __forceinline__ uint f2bf(float x) {
    uint u = __float_as_uint(x);
    return (u + 0x7fffu + ((u >> 16) & 1u)) >> 16;
}
__device__ __forceinline__ float bflo(uint v) { return __uint_as_float(v << 16); }
__device__ __forceinline__ float bfhi(uint v) { return __uint_as_float(v & 0xffff0000u); }

// async global->LDS 16B per lane: dest = lds_base(wave-uniform) + lane*16
__device__ __forceinline__ void gload16(const ushort* g, ushort* l) {
    __builtin_amdgcn_global_load_lds((const __attribute__((address_space(1))) uint*)g,
                                     (__attribute__((address_space(3))) uint*)l, 16, 0, 0);
}

// ---------------- fp32 -> bf16 conversion (both node types, one dispatch) ----------------
__global__ void f2b2(const float4* __restrict__ x0, const float4* __restrict__ x1,
                     uint2* __restrict__ o0, uint2* __restrict__ o1, int n4) {
    int y = blockIdx.y;
    const float4* in = y ? x1 : x0;
    uint2* out = y ? o1 : o0;
    int i = blockIdx.x * blockDim.x + threadIdx.x;
    int stride = gridDim.x * blockDim.x;
    for (; i < n4; i += stride) {
        float4 v = in[i];
        uint2 o;
        o.x = f2bf(v.x) | (f2bf(v.y) << 16);
        o.y = f2bf(v.z) | (f2bf(v.w) << 16);
        out[i] = o;
    }
}

// ---------------- CSR build via two-pass counting sort (packed 4B records) ----------------

__global__ void bhist3(const int* __restrict__ e0, const int* __restrict__ e1,
                       const int* __restrict__ e2, int E, int NB, int* __restrict__ bcnt) {
    int m = blockIdx.y;
    const int* dst = (m == 0 ? e0 : (m == 1 ? e1 : e2)) + E;
    __shared__ int h[NBMAX];
    int tid = threadIdx.x;
    if (tid < NB) h[tid] = 0;
    __syncthreads();
    int i = blockIdx.x * blockDim.x + tid, st = gridDim.x * blockDim.x;
    for (; i < E; i += st) atomicAdd(&h[dst[i] >> BSH], 1);
    __syncthreads();
    if (tid < NB && h[tid]) atomicAdd(&bcnt[m * NB + tid], h[tid]);
}

__global__ void bscan(const int* __restrict__ bcnt, int* __restrict__ bso,
                      int* __restrict__ gcur, int NB) {
    int m = threadIdx.x;
    if (m >= 3) return;
    int acc = 0;
    for (int b = 0; b < NB; ++b) {
        bso[m * (NB + 1) + b] = acc;
        gcur[m * NB + b] = acc;
        acc += bcnt[m * NB + b];
    }
    bso[m * (NB + 1) + NB] = acc;
}

// record: src (16b) | dst-low-9 << 16   (requires N <= 65536)
#define BIN_CH 16
__global__ __launch_bounds__(256) void bin3(const int* __restrict__ e0, const int* __restrict__ e1,
                                            const int* __restrict__ e2, int E, int NB,
                                            int* __restrict__ gcur, uint* __restrict__ pairs) {
    int m = blockIdx.y;
    const int* eb = (m == 0 ? e0 : (m == 1 ? e1 : e2));
    const int* src = eb;
    const int* dst = eb + E;
    uint* pp = pairs + (size_t)m * E;
    int* gc = gcur + m * NB;
    __shared__ int h[NBMAX], base[NBMAX], pos[NBMAX];
    int tid = threadIdx.x;
    if (tid < NB) { h[tid] = 0; pos[tid] = 0; }
    __syncthreads();
    int i0 = blockIdx.x * (256 * BIN_CH);
    uint pk[BIN_CH];
    int bk[BIN_CH];
    #pragma unroll
    for (int u = 0; u < BIN_CH; ++u) {
        int i = i0 + u * 256 + tid;
        bk[u] = -1;
        if (i < E) {
            int s = src[i], d = dst[i];
            bk[u] = d >> BSH;
            pk[u] = (uint)s | ((uint)(d & ((1 << BSH) - 1)) << 16);
            atomicAdd(&h[bk[u]], 1);
        }
    }
    __syncthreads();
    if (tid < NB && h[tid]) base[tid] = atomicAdd(&gc[tid], h[tid]);
    __syncthreads();
    #pragma unroll
    for (int u = 0; u < BIN_CH; ++u) {
        if (bk[u] >= 0) {
            int p = base[bk[u]] + atomicAdd(&pos[bk[u]], 1);
            pp[p] = pk[u];
        }
    }
}

__global__ __launch_bounds__(256) void csr3(const uint* __restrict__ pairs, const int* __restrict__ bso,
                                            int E, int N, int NB,
                                            int* __restrict__ offs, ushort* __restrict__ srcs) {
    int m = blockIdx.y, b = blockIdx.x;
    const uint* pp = pairs + (size_t)m * E;
    int gstart = bso[m * (NB + 1) + b];
    int gend = bso[m * (NB + 1) + b + 1];
    int cnt = gend - gstart;
    if (cnt > BCAP) cnt = BCAP;
    int d0 = b << BSH;
    int dcnt = N - d0;
    if (dcnt > (1 << BSH)) dcnt = 1 << BSH;

    __shared__ int hist[1 << BSH], po[1 << BSH], off0[1 << BSH];
    __shared__ int lsort[BCAP];
    __shared__ int wsum[4];
    int tid = threadIdx.x;
    hist[tid] = 0;
    hist[tid + 256] = 0;
    __syncthreads();
    for (int i = tid; i < cnt; i += 256) atomicAdd(&hist[pp[gstart + i] >> 16], 1);
    __syncthreads();
    int a = hist[2 * tid], b2 = hist[2 * tid + 1];
    int s = a + b2;
    int lane = tid & 63, w = tid >> 6;
    #pragma unroll
    for (int o = 1; o < 64; o <<= 1) {
        int v = __shfl_up(s, o, 64);
        if (lane >= o) s += v;
    }
    if (lane == 63) wsum[w] = s;
    __syncthreads();
    int wp = 0;
    #pragma unroll
    for (int q = 0; q < 4; ++q)
        if (q < w) wp += wsum[q];
    int excl = wp + s - a - b2;
    off0[2 * tid] = excl; off0[2 * tid + 1] = excl + a;
    po[2 * tid] = excl;   po[2 * tid + 1] = excl + a;
    __syncthreads();
    for (int j = tid; j < dcnt; j += 256) offs[(size_t)m * (N + 1) + d0 + j] = gstart + off0[j];
    if (b == NB - 1 && tid == 0) offs[(size_t)m * (N + 1) + N] = bso[m * (NB + 1) + NB];
    for (int i = tid; i < cnt; i += 256) {
        uint e = pp[gstart + i];
        int p = atomicAdd(&po[e >> 16], 1);
        if (p < BCAP) lsort[p] = (int)(e & 0xffffu);
    }
    __syncthreads();
    for (int i = tid; i < cnt; i += 256) srcs[(size_t)m * E + gstart + i] = (ushort)lsort[i];
}

// ---------------- segment mean: 4 rows/wave (16 lanes x uint4 = 256B row), 4-unrolled ----------------
__global__ void agg3(const ushort* __restrict__ s0, const ushort* __restrict__ s1,
                     const ushort* __restrict__ s2,
                     uint* __restrict__ o0, uint* __restrict__ o1, uint* __restrict__ o2,
                     const int* __restrict__ offs, const ushort* __restrict__ srcs,
                     int n, int E) {
    int m = blockIdx.y;
    const uint4* x = (const uint4*)(m == 0 ? s0 : (m == 1 ? s1 : s2));
    uint4* o = (uint4*)(m == 0 ? o0 : (m == 1 ? o1 : o2));
    const int* off = offs + (size_t)m * (n + 1);
    const ushort* sl = srcs + (size_t)m * E;

    int tid = threadIdx.x;
    int l16 = tid & 15;
    int row = blockIdx.x * 16 + (tid >> 4);
    if (row >= n) return;
    int s = off[row], e = off[row + 1];
    float a0 = 0, a1 = 0, a2 = 0, a3 = 0, a4 = 0, a5 = 0, a6 = 0, a7 = 0;
    int i = s;
    for (; i + 3 < e; i += 4) {
        int j0 = sl[i], j1 = sl[i + 1], j2 = sl[i + 2], j3 = sl[i + 3];
        uint4 v0 = x[(size_t)j0 * 16 + l16];
        uint4 v1 = x[(size_t)j1 * 16 + l16];
        uint4 v2 = x[(size_t)j2 * 16 + l16];
        uint4 v3 = x[(size_t)j3 * 16 + l16];
        a0 += (bflo(v0.x) + bflo(v1.x)) + (bflo(v2.x) + bflo(v3.x));
        a1 += (bfhi(v0.x) + bfhi(v1.x)) + (bfhi(v2.x) + bfhi(v3.x));
        a2 += (bflo(v0.y) + bflo(v1.y)) + (bflo(v2.y) + bflo(v3.y));
        a3 += (bfhi(v0.y) + bfhi(v1.y)) + (bfhi(v2.y) + bfhi(v3.y));
        a4 += (bflo(v0.z) + bflo(v1.z)) + (bflo(v2.z) + bflo(v3.z));
        a5 += (bfhi(v0.z) + bfhi(v1.z)) + (bfhi(v2.z) + bfhi(v3.z));
        a6 += (bflo(v0.w) + bflo(v1.w)) + (bflo(v2.w) + bflo(v3.w));
        a7 += (bfhi(v0.w) + bfhi(v1.w)) + (bfhi(v2.w) + bfhi(v3.w));
    }
    for (; i < e; ++i) {
        uint4 v = x[(size_t)sl[i] * 16 + l16];
        a0 += bflo(v.x); a1 += bfhi(v.x);
        a2 += bflo(v.y); a3 += bfhi(v.y);
        a4 += bflo(v.z); a5 += bfhi(v.z);
        a6 += bflo(v.w); a7 += bfhi(v.w);
    }
    int d = e - s;
    float inv = 1.f / (float)(d > 0 ? d : 1);
    uint4 r;
    r.x = f2bf(a0 * inv) | (f2bf(a1 * inv) << 16);
    r.y = f2bf(a2 * inv) | (f2bf(a3 * inv) << 16);
    r.z = f2bf(a4 * inv) | (f2bf(a5 * inv) << 16);
    r.w = f2bf(a6 * inv) | (f2bf(a7 * inv) << 16);
    o[(size_t)row * 16 + l16] = r;
}

// ---------------- weight fusion ----------------
__global__ void fuseW(const float* __restrict__ Wn1, const float* __restrict__ Ws1,
                      const float* __restrict__ Wu1,
                      const float* __restrict__ Wn2, const float* __restrict__ Ws2,
                      const float* __restrict__ Wu2, ushort* __restrict__ FT) {
    int j5 = blockIdx.y;
    int l = j5 / 5, t = j5 - l * 5;
    const float* Wn = l ? Wn2 : Wn1;
    const float* Ws = l ? Ws2 : Ws1;
    const float* Wu = l ? Wu2 : Wu1;
    const float *A0, *B0, *A1 = nullptr, *B1 = nullptr;
    float al;
    switch (t) {
        case 0: A0 = Wn;          B0 = Wu;          al = 1.0f; break;
        case 1: A0 = Wn + 16384;  B0 = Wu + 32768;  al = 0.5f; break;
        case 2: A0 = Wn + 32768;  B0 = Wu + 65536;  al = 0.5f; break;
        case 3: A0 = Ws;          B0 = Wu + 16384;  al = 1.0f; break;
        default:
            A0 = Ws + 16384; B0 = Wu + 49152;
            A1 = Ws + 32768; B1 = Wu + 81920;
            al = 0.5f; break;
    }
    int i = blockIdx.x, j = threadIdx.x;
    float s0 = 0, s1 = 0, s2 = 0, s3 = 0;
    #pragma unroll 4
    for (int k = 0; k < 128; k += 4) {
        s0 += A0[i * 128 + k]     * B0[k * 128 + j];
        s1 += A0[i * 128 + k + 1] * B0[(k + 1) * 128 + j];
        s2 += A0[i * 128 + k + 2] * B0[(k + 2) * 128 + j];
        s3 += A0[i * 128 + k + 3] * B0[(k + 3) * 128 + j];
    }
    if (A1) {
        #pragma unroll 4
        for (int k = 0; k < 128; k += 4) {
            s0 += A1[i * 128 + k]     * B1[k * 128 + j];
            s1 += A1[i * 128 + k + 1] * B1[(k + 1) * 128 + j];
            s2 += A1[i * 128 + k + 2] * B1[(k + 2) * 128 + j];
            s3 += A1[i * 128 + k + 3] * B1[(k + 3) * 128 + j];
        }
    }
    float r = al * ((s0 + s1) + (s2 + s3));
    FT[(size_t)j5 * 16384 + j * 128 + i] = (ushort)f2bf(r);
}

__global__ void fuseB(const float* __restrict__ bn1, const float* __restrict__ bs1,
                      const float* __restrict__ bu1, const float* __restrict__ Wu1,
                      const float* __restrict__ bn2, const float* __restrict__ bs2,
                      const float* __restrict__ bu2, const float* __restrict__ Wu2,
                      float* __restrict__ FC) {
    int jb = blockIdx.x;
    int l = jb >> 1, which = jb & 1;
    const float* bn = l ? bn2 : bn1;
    const float* bs = l ? bs2 : bs1;
    const float* bu = l ? bu2 : bu1;
    const float* Wu = l ? Wu2 : Wu1;
    int j = threadIdx.x;
    float s = 0.f;
    if (which == 0) {
        s = bu[j];
        for (int k = 0; k < 128; ++k)
            s += bn[k] * Wu[k * 128 + j] + bs[k] * Wu[(128 + k) * 128 + j];
    } else {
        #pragma unroll
        for (int tt = 1; tt <= 2; ++tt) {
            const float* Wt = Wu + tt * 32768;
            float p = bu[tt * 128 + j];
            for (int k = 0; k < 128; ++k)
                p += bn[tt * 128 + k] * Wt[k * 128 + j] + bs[tt * 128 + k] * Wt[(128 + k) * 128 + j];
            s += 0.5f * p;
        }
    }
    FC[jb * 128 + j] = s;
}

// ---------------- batched MFMA GEMM: double-buffered global_load_lds staging ----------------
__global__ __launch_bounds__(256) void gemm2_mfma(
    const ushort* __restrict__ Aq0, const ushort* __restrict__ Wq0,
    const ushort* __restrict__ Aq1, const ushort* __restrict__ Wq1,
    const ushort* __restrict__ Ap0, const ushort* __restrict__ Wp0,
    const ushort* __restrict__ Ap1, const ushort* __restrict__ Wp1,
    const ushort* __restrict__ Ap2, const ushort* __restrict__ Wp2,
    const float* __restrict__ biasq, const float* __restrict__ biasp,
    ushort* __restrict__ Cq, ushort* __restrict__ Cp, int M,
    float* __restrict__ STW) {
    __shared__ ushort As[2][64 * 128];
    int y = blockIdx.y;
    const float* bias = y ? biasp : biasq;
    ushort* C = y ? Cp : Cq;
    float* colsum = STW + (size_t)(blockIdx.x & 31) * 512 + (y ? 0 : 256);
    float* colsq = colsum + 128;

    int tid = threadIdx.x;
    int wid = tid >> 6;
    int lane = tid & 63;
    int l15 = lane & 15, lg = lane >> 4;
    int row0 = blockIdx.x * 64;
    int nIn = y ? 3 : 2;

    const ushort* Ax[3];
    const ushort* Wx[3];
    Ax[0] = y ? Ap0 : Aq0;  Wx[0] = y ? Wp0 : Wq0;
    Ax[1] = y ? Ap1 : Aq1;  Wx[1] = y ? Wp1 : Wq1;
    Ax[2] = Ap2;            Wx[2] = Wp2;

    auto stage = [&](const ushort* A, ushort* buf) {
        #pragma unroll
        for (int p = 0; p < 4; ++p) {
            int row = wid * 16 + p * 4 + (lane >> 4);
            int gr = row0 + row;
            if (gr > M - 1) gr = M - 1;
            const ushort* src = A + (size_t)gr * 128 + (((lane & 15) ^ (row & 7)) * 8);
            gload16(src, buf + (wid * 4 + p) * 512);
        }
    };

    f32x4 acc[4][2];
    #pragma unroll
    for (int rb = 0; rb < 4; ++rb)
        #pragma unroll
        for (int cb = 0; cb < 2; ++cb) acc[rb][cb] = (f32x4){0.f, 0.f, 0.f, 0.f};

    stage(Ax[0], As[0]);
    __syncthreads();
    int cur = 0;

    #pragma unroll
    for (int inp = 0; inp < 3; ++inp) {
        if (inp == 2 && nIn == 2) break;   // wave-uniform
        const ushort* W = Wx[inp];
        short8 bw[4][2];
        #pragma unroll
        for (int k0 = 0; k0 < 4; ++k0)
            #pragma unroll
            for (int cb = 0; cb < 2; ++cb)
                bw[k0][cb] = *(const short8*)(W + (size_t)(wid * 32 + cb * 16 + l15) * 128 + k0 * 32 + lg * 8);
        if (inp + 1 < nIn) stage(Ax[inp + 1], As[cur ^ 1]);
        #pragma unroll
        for (int k0 = 0; k0 < 4; ++k0) {
            short8 a[4];
            #pragma unroll
            for (int rb = 0; rb < 4; ++rb)
                a[rb] = *(const short8*)&As[cur][(rb * 16 + l15) * 128 + (((k0 * 4 + lg) ^ (l15 & 7)) * 8)];
            #pragma unroll
            for (int rb = 0; rb < 4; ++rb)
                #pragma unroll
                for (int cb = 0; cb < 2; ++cb)
                    acc[rb][cb] = __builtin_amdgcn_mfma_f32_16x16x32_bf16(a[rb], bw[k0][cb], acc[rb][cb], 0, 0, 0);
        }
        __syncthreads();
        cur ^= 1;
    }

    float ps[2] = {0.f, 0.f}, pq[2] = {0.f, 0.f};
    int colbase = wid * 32;
    #pragma unroll
    for (int cb = 0; cb < 2; ++cb) {
        int col = colbase + cb * 16 + l15;
        float b = bias[col];
        #pragma unroll
        for (int rb = 0; rb < 4; ++rb) {
            int rbase = row0 + rb * 16 + lg * 4;
            #pragma unroll
            for (int i = 0; i < 4; ++i) {
                int r = rbase + i;
                if (r < M) {
                    float v = acc[rb][cb][i] + b;
                    C[(size_t)r * 128 + col] = (ushort)f2bf(v);
                    ps[cb] += v;
                    pq[cb] += v * v;
                }
            }
        }
    }
    #pragma unroll
    for (int cb = 0; cb < 2; ++cb) {
        ps[cb] += __shfl_xor(ps[cb], 16, 64);
        ps[cb] += __shfl_xor(ps[cb], 32, 64);
        pq[cb] += __shfl_xor(pq[cb], 16, 64);
        pq[cb] += __shfl_xor(pq[cb], 32, 64);
    }
    if (lane < 16) {
        atomicAdd(&colsum[colbase + lane], ps[0]);
        atomicAdd(&colsq[colbase + lane], pq[0]);
        atomicAdd(&colsum[colbase + 16 + lane], ps[1]);
        atomicAdd(&colsq[colbase + 16 + lane], pq[1]);
    }
}

// ---------------- BN finalize: reduce 32 shadow copies, self-zero for next layer ----------------
__global__ void bn_fin2(float* __restrict__ STW, float* __restrict__ ST,
                        const float* __restrict__ g0, const float* __restrict__ b0,
                        const float* __restrict__ g1, const float* __restrict__ b1, int N) {
    int tid = threadIdx.x;
    int which = tid >> 7, c = tid & 127;
    float s = 0.f, q = 0.f;
    #pragma unroll 8
    for (int cp = 0; cp < 32; ++cp) {
        s += STW[(size_t)cp * 512 + which * 256 + c];
        q += STW[(size_t)cp * 512 + which * 256 + 128 + c];
    }
    #pragma unroll 8
    for (int cp = 0; cp < 32; ++cp) {
        STW[(size_t)cp * 512 + which * 256 + c] = 0.f;
        STW[(size_t)cp * 512 + which * 256 + 128 + c] = 0.f;
    }
    const float* g = which ? g1 : g0;
    const float* b = which ? b1 : b0;
    float m = s / (float)N;
    float v = q / (float)N - m * m;
    float rs = rsqrtf(v + 1e-5f);
    float sc = g[c] * rs;
    ST[512 + which * 256 + c] = sc;
    ST[640 + which * 256 + c] = b[c] - m * sc;
}

// ---------------- BN apply + LeakyReLU: bf16 in -> bf16 out (layer 1 only) ----------------
__global__ void bn_apply2(const ushort* __restrict__ Cp, ushort* __restrict__ X0b,
                          const ushort* __restrict__ Cq, ushort* __restrict__ X1b,
                          const float* __restrict__ ST, int n4) {
    int y = blockIdx.y;
    const uint2* in = (const uint2*)(y ? Cq : Cp);
    uint2* out = (uint2*)(y ? X1b : X0b);
    const float* sc = ST + 512 + y * 256;
    const float* sh = sc + 128;
    int i = blockIdx.x * blockDim.x + threadIdx.x;
    int stride = gridDim.x * blockDim.x;
    for (; i < n4; i += stride) {
        uint2 v = in[i];
        int cb = (i * 4) & 127;
        float4 s4 = *(const float4*)&sc[cb];
        float4 h4 = *(const float4*)&sh[cb];
        float y0 = bflo(v.x) * s4.x + h4.x;
        float y1 = bfhi(v.x) * s4.y + h4.y;
        float y2 = bflo(v.y) * s4.z + h4.z;
        float y3 = bfhi(v.y) * s4.w + h4.w;
        y0 = (y0 >= 0.f) ? y0 : 0.01f * y0;
        y1 = (y1 >= 0.f) ? y1 : 0.01f * y1;
        y2 = (y2 >= 0.f) ? y2 : 0.01f * y2;
        y3 = (y3 >= 0.f) ? y3 : 0.01f * y3;
        uint2 o;
        o.x = f2bf(y0) | (f2bf(y1) << 16);
        o.y = f2bf(y2) | (f2bf(y3) << 16);
        out[i] = o;
    }
}

// ---------------- fused BN + LeakyReLU + projection (layer 2), both types ----------------
__global__ void projbn2(const ushort* __restrict__ Cp, const ushort* __restrict__ Cq,
                        const float* __restrict__ ST,
                        const float* __restrict__ Wp, const float* __restrict__ bp,
                        float* __restrict__ out, int N) {
    int y = blockIdx.y;
    const uint* h = (const uint*)(y ? Cq : Cp);
    const float* W = Wp + y * 1024;
    const float* b = bp + y * 8;
    float* op = out + (size_t)y * N * 8;
    __shared__ float Wsh[1024];
    __shared__ float scs[128], shs[128];
    __shared__ float bsh[8];
    int tid = threadIdx.x;
    for (int i = tid; i < 1024; i += 256) Wsh[i] = W[i];
    if (tid < 128) {
        scs[tid] = ST[512 + y * 256 + tid];
        shs[tid] = ST[640 + y * 256 + tid];
    }
    if (tid < 8) bsh[tid] = b[tid];
    __syncthreads();
    int idx = blockIdx.x * 256 + tid;
    if (idx >= N * LBL) return;
    int r = idx >> 3, c = idx & 7;
    const uint* hr = h + (size_t)r * 64;
    float s = bsh[c];
    #pragma unroll
    for (int k2 = 0; k2 < 64; ++k2) {
        uint v = hr[k2];
        float xa = bflo(v) * scs[2 * k2] + shs[2 * k2];
        float xb = bfhi(v) * scs[2 * k2 + 1] + shs[2 * k2 + 1];
        xa = (xa >= 0.f) ? xa : 0.01f * xa;
        xb = (xb >= 0.f) ? xb : 0.01f * xb;
        s += xa * Wsh[(2 * k2) * 8 + c] + xb * Wsh[(2 * k2 + 1) * 8 + c];
    }
    op[idx] = s;
}

// ---------------- host ----------------

extern "C" void kernel_launch(void* const* d_in, const int* in_sizes, int n_in,
                              void* d_out, int out_size, void* d_ws, size_t ws_size,
                              hipStream_t stream) {
    const float* x0 = (const float*)d_in[0];
    const float* x1 = (const float*)d_in[1];
    const float* Wn1 = (const float*)d_in[2];
    const float* Ws1 = (const float*)d_in[3];
    const float* Wu1 = (const float*)d_in[4];
    const float* Wn2 = (const float*)d_in[5];
    const float* Ws2 = (const float*)d_in[6];
    const float* Wu2 = (const float*)d_in[7];
    const float* bnn[2] = {(const float*)d_in[8], (const float*)d_in[11]};
    const float* bss[2] = {(const float*)d_in[9], (const float*)d_in[12]};
    const float* buu[2] = {(const float*)d_in[10], (const float*)d_in[13]};
    const float* gam[2] = {(const float*)d_in[14], (const float*)d_in[16]};
    const float* bet[2] = {(const float*)d_in[15], (const float*)d_in[17]};
    const float* Wp = (const float*)d_in[18];
    const float* bp = (const float*)d_in[19];
    const int* ei[3] = {(const int*)d_in[20], (const int*)d_in[21], (const int*)d_in[22]};

    const int N = in_sizes[0] / 128;
    const int E = in_sizes[20] / 2;
    const int NB = (N + (1 << BSH) - 1) >> BSH;
    float* out = (float*)d_out;

    char* wp_ = (char*)d_ws;
    auto carve = [&](size_t bytes) {
        char* r = wp_;
        wp_ += (bytes + 255) & ~(size_t)255;
        return r;
    };
    size_t nodeB = (size_t)N * 128 * sizeof(ushort);
    ushort* Cp = (ushort*)carve(nodeB);   // h0pre bf16 (pairs aliases this early)
    ushort* Cq = (ushort*)carve(nodeB);   // h1pre bf16
    ushort* Pb = (ushort*)carve(nodeB);
    ushort* Rb = (ushort*)carve(nodeB);
    ushort* Sb = (ushort*)carve(nodeB);
    ushort* X0b = (ushort*)carve(nodeB);
    ushort* X1b = (ushort*)carve(nodeB);
    ushort* x0b = (ushort*)carve(nodeB);
    ushort* x1b = (ushort*)carve(nodeB);
    ushort* FT = (ushort*)carve(10 * 16384 * 2);
    float* FC = (float*)carve(4 * 128 * 4);
    float* ST = (float*)carve(1024 * 4);           // scale/shift region
    float* STW = (float*)carve(32 * 512 * 4);      // 32 shadow BN-stat copies
    int* offs = (int*)carve((size_t)3 * (N + 1) * 4);
    ushort* srcs = (ushort*)carve((size_t)3 * E * 2);
    int* bcnt = (int*)carve((size_t)3 * NB * 4);
    int* bso = (int*)carve((size_t)3 * (NB + 1) * 4);
    int* gcur = (int*)carve((size_t)3 * NB * 4);
    uint* pairs = (uint*)Cp;  // 3*E*4 = 6 MB <= nodeB (12.8 MB); dead before gemm writes Cp

    const int ag = (N + 15) / 16;
    const int gg = (N + 63) / 64;
    const int pg = (N * LBL + 255) / 256;
    const int bg = (E + 256 * BIN_CH - 1) / (256 * BIN_CH);

    f2b2<<<dim3(1024, 2), 256, 0, stream>>>((const float4*)x0, (const float4*)x1,
                                            (uint2*)x0b, (uint2*)x1b, N * 32);

    hipMemsetAsync(bcnt, 0, (size_t)3 * NB * 4, stream);
    hipMemsetAsync(STW, 0, 32 * 512 * 4, stream);
    bhist3<<<dim3(512, 3), 256, 0, stream>>>(ei[0], ei[1], ei[2], E, NB, bcnt);
    bscan<<<1, 64, 0, stream>>>(bcnt, bso, gcur, NB);
    bin3<<<dim3(bg, 3), 256, 0, stream>>>(ei[0], ei[1], ei[2], E, NB, gcur, pairs);
    csr3<<<dim3(NB, 3), 256, 0, stream>>>(pairs, bso, E, N, NB, offs, srcs);

    fuseW<<<dim3(128, 10), 128, 0, stream>>>(Wn1, Ws1, Wu1, Wn2, Ws2, Wu2, FT);
    fuseB<<<4, 128, 0, stream>>>(bnn[0], bss[0], buu[0], Wu1, bnn[1], bss[1], buu[1], Wu2, FC);

    const ushort* srcS[2][3] = {{x0b, x1b, x0b}, {X0b, X1b, X0b}};
    const ushort* dstX[2][2] = {{x0b, x1b}, {X0b, X1b}};

    for (int l = 0; l < 2; ++l) {
        const ushort* FA0T = FT + (size_t)(l * 5 + 0) * 16384;
        const ushort* FA1T = FT + (size_t)(l * 5 + 1) * 16384;
        const ushort* FA2T = FT + (size_t)(l * 5 + 2) * 16384;
        const ushort* FB1T = FT + (size_t)(l * 5 + 3) * 16384;
        const ushort* FB0T = FT + (size_t)(l * 5 + 4) * 16384;
        const float* fcH1 = FC + (l * 2 + 0) * 128;
        const float* fcH0 = FC + (l * 2 + 1) * 128;

        agg3<<<dim3(ag, 3), 256, 0, stream>>>(srcS[l][0], srcS[l][1], srcS[l][2],
                                              (uint*)Pb, (uint*)Rb, (uint*)Sb,
                                              offs, srcs, N, E);

        // y=0: Cq = Pb@FA0 + x1@FB1 ; y=1: Cp = Rb@FA1 + Sb@FA2 + x0@FB0
        gemm2_mfma<<<dim3(gg, 2), 256, 0, stream>>>(
            Pb, FA0T, dstX[l][1], FB1T,
            Rb, FA1T, Sb, FA2T, dstX[l][0], FB0T,
            fcH1, fcH0, Cq, Cp, N, STW);

        bn_fin2<<<1, 256, 0, stream>>>(STW, ST, gam[l], bet[l], gam[l] + 128, bet[l] + 128, N);
        if (l == 0)
            bn_apply2<<<dim3(1024, 2), 256, 0, stream>>>(Cp, X0b, Cq, X1b, ST, N * 32);
    }

    // layer-2 BN + LeakyReLU fused into the projection
    projbn2<<<dim3(pg, 2), 256, 0, stream>>>(Cp, Cq, ST, Wp, bp, out, N);
}

// Round 14
// 299.315 us; speedup vs baseline: 1.0879x; 1.0302x over previous
//
#include <hip/hip_runtime.h>

#define LBL 8
#define NBMAX 128
#define BSH 9            // 512 dsts per bucket
#define BCAP 8192        // LDS sort capacity per bucket (mean ~5100)

typedef __attribute__((ext_vector_type(8))) short short8;
typedef __attribute__((ext_vector_type(4))) float f32x4;

__device__ __forceinline__ uint f2bf(float x) {
    uint u = __float_as_uint(x);
    return (u + 0x7fffu + ((u >> 16) & 1u)) >> 16;
}
__device__ __forceinline__ float bflo(uint v) { return __uint_as_float(v << 16); }
__device__ __forceinline__ float bfhi(uint v) { return __uint_as_float(v & 0xffff0000u); }

// async global->LDS 16B per lane: dest = lds_base(wave-uniform) + lane*16
__device__ __forceinline__ void gload16(const ushort* g, ushort* l) {
    __builtin_amdgcn_global_load_lds((const __attribute__((address_space(1))) uint*)g,
                                     (__attribute__((address_space(3))) uint*)l, 16, 0, 0);
}

// ---------------- fp32 -> bf16 conversion (both node types, one dispatch) ----------------
__global__ void f2b2(const float4* __restrict__ x0, const float4* __restrict__ x1,
                     uint2* __restrict__ o0, uint2* __restrict__ o1, int n4) {
    int y = blockIdx.y;
    const float4* in = y ? x1 : x0;
    uint2* out = y ? o1 : o0;
    int i = blockIdx.x * blockDim.x + threadIdx.x;
    int stride = gridDim.x * blockDim.x;
    for (; i < n4; i += stride) {
        float4 v = in[i];
        uint2 o;
        o.x = f2bf(v.x) | (f2bf(v.y) << 16);
        o.y = f2bf(v.z) | (f2bf(v.w) << 16);
        out[i] = o;
    }
}

// ---------------- CSR build via two-pass counting sort (packed 4B records) ----------------

__global__ void bhist3(const int* __restrict__ e0, const int* __restrict__ e1,
                       const int* __restrict__ e2, int E, int NB, int* __restrict__ bcnt) {
    int m = blockIdx.y;
    const int* dst = (m == 0 ? e0 : (m == 1 ? e1 : e2)) + E;
    __shared__ int h[NBMAX];
    int tid = threadIdx.x;
    if (tid < NB) h[tid] = 0;
    __syncthreads();
    int i = blockIdx.x * blockDim.x + tid, st = gridDim.x * blockDim.x;
    for (; i < E; i += st) atomicAdd(&h[dst[i] >> BSH], 1);
    __syncthreads();
    if (tid < NB && h[tid]) atomicAdd(&bcnt[m * NB + tid], h[tid]);
}

__global__ void bscan(const int* __restrict__ bcnt, int* __restrict__ bso,
                      int* __restrict__ gcur, int NB) {
    int m = threadIdx.x;
    if (m >= 3) return;
    int acc = 0;
    for (int b = 0; b < NB; ++b) {
        bso[m * (NB + 1) + b] = acc;
        gcur[m * NB + b] = acc;
        acc += bcnt[m * NB + b];
    }
    bso[m * (NB + 1) + NB] = acc;
}

// record: src (16b) | dst-low-9 << 16   (requires N <= 65536)
#define BIN_CH 16
__global__ __launch_bounds__(256) void bin3(const int* __restrict__ e0, const int* __restrict__ e1,
                                            const int* __restrict__ e2, int E, int NB,
                                            int* __restrict__ gcur, uint* __restrict__ pairs) {
    int m = blockIdx.y;
    const int* eb = (m == 0 ? e0 : (m == 1 ? e1 : e2));
    const int* src = eb;
    const int* dst = eb + E;
    uint* pp = pairs + (size_t)m * E;
    int* gc = gcur + m * NB;
    __shared__ int h[NBMAX], base[NBMAX], pos[NBMAX];
    int tid = threadIdx.x;
    if (tid < NB) { h[tid] = 0; pos[tid] = 0; }
    __syncthreads();
    int i0 = blockIdx.x * (256 * BIN_CH);
    uint pk[BIN_CH];
    int bk[BIN_CH];
    #pragma unroll
    for (int u = 0; u < BIN_CH; ++u) {
        int i = i0 + u * 256 + tid;
        bk[u] = -1;
        if (i < E) {
            int s = src[i], d = dst[i];
            bk[u] = d >> BSH;
            pk[u] = (uint)s | ((uint)(d & ((1 << BSH) - 1)) << 16);
            atomicAdd(&h[bk[u]], 1);
        }
    }
    __syncthreads();
    if (tid < NB && h[tid]) base[tid] = atomicAdd(&gc[tid], h[tid]);
    __syncthreads();
    #pragma unroll
    for (int u = 0; u < BIN_CH; ++u) {
        if (bk[u] >= 0) {
            int p = base[bk[u]] + atomicAdd(&pos[bk[u]], 1);
            pp[p] = pk[u];
        }
    }
}

__global__ __launch_bounds__(256) void csr3(const uint* __restrict__ pairs, const int* __restrict__ bso,
                                            int E, int N, int NB,
                                            int* __restrict__ offs, ushort* __restrict__ srcs) {
    int m = blockIdx.y, b = blockIdx.x;
    const uint* pp = pairs + (size_t)m * E;
    int gstart = bso[m * (NB + 1) + b];
    int gend = bso[m * (NB + 1) + b + 1];
    int cnt = gend - gstart;
    if (cnt > BCAP) cnt = BCAP;
    int d0 = b << BSH;
    int dcnt = N - d0;
    if (dcnt > (1 << BSH)) dcnt = 1 << BSH;

    __shared__ int hist[1 << BSH], po[1 << BSH], off0[1 << BSH];
    __shared__ int lsort[BCAP];
    __shared__ int wsum[4];
    int tid = threadIdx.x;
    hist[tid] = 0;
    hist[tid + 256] = 0;
    __syncthreads();
    for (int i = tid; i < cnt; i += 256) atomicAdd(&hist[pp[gstart + i] >> 16], 1);
    __syncthreads();
    int a = hist[2 * tid], b2 = hist[2 * tid + 1];
    int s = a + b2;
    int lane = tid & 63, w = tid >> 6;
    #pragma unroll
    for (int o = 1; o < 64; o <<= 1) {
        int v = __shfl_up(s, o, 64);
        if (lane >= o) s += v;
    }
    if (lane == 63) wsum[w] = s;
    __syncthreads();
    int wp = 0;
    #pragma unroll
    for (int q = 0; q < 4; ++q)
        if (q < w) wp += wsum[q];
    int excl = wp + s - a - b2;
    off0[2 * tid] = excl; off0[2 * tid + 1] = excl + a;
    po[2 * tid] = excl;   po[2 * tid + 1] = excl + a;
    __syncthreads();
    for (int j = tid; j < dcnt; j += 256) offs[(size_t)m * (N + 1) + d0 + j] = gstart + off0[j];
    if (b == NB - 1 && tid == 0) offs[(size_t)m * (N + 1) + N] = bso[m * (NB + 1) + NB];
    for (int i = tid; i < cnt; i += 256) {
        uint e = pp[gstart + i];
        int p = atomicAdd(&po[e >> 16], 1);
        if (p < BCAP) lsort[p] = (int)(e & 0xffffu);
    }
    __syncthreads();
    for (int i = tid; i < cnt; i += 256) srcs[(size_t)m * E + gstart + i] = (ushort)lsort[i];
}

// ---------------- segment mean: 4 rows/wave (16 lanes x uint4 = 256B row), 4-unrolled ----------------
__global__ void agg3(const ushort* __restrict__ s0, const ushort* __restrict__ s1,
                     const ushort* __restrict__ s2,
                     uint* __restrict__ o0, uint* __restrict__ o1, uint* __restrict__ o2,
                     const int* __restrict__ offs, const ushort* __restrict__ srcs,
                     int n, int E) {
    int m = blockIdx.y;
    const uint4* x = (const uint4*)(m == 0 ? s0 : (m == 1 ? s1 : s2));
    uint4* o = (uint4*)(m == 0 ? o0 : (m == 1 ? o1 : o2));
    const int* off = offs + (size_t)m * (n + 1);
    const ushort* sl = srcs + (size_t)m * E;

    int tid = threadIdx.x;
    int l16 = tid & 15;
    int row = blockIdx.x * 16 + (tid >> 4);
    if (row >= n) return;
    int s = off[row], e = off[row + 1];
    float a0 = 0, a1 = 0, a2 = 0, a3 = 0, a4 = 0, a5 = 0, a6 = 0, a7 = 0;
    int i = s;
    for (; i + 3 < e; i += 4) {
        int j0 = sl[i], j1 = sl[i + 1], j2 = sl[i + 2], j3 = sl[i + 3];
        uint4 v0 = x[(size_t)j0 * 16 + l16];
        uint4 v1 = x[(size_t)j1 * 16 + l16];
        uint4 v2 = x[(size_t)j2 * 16 + l16];
        uint4 v3 = x[(size_t)j3 * 16 + l16];
        a0 += (bflo(v0.x) + bflo(v1.x)) + (bflo(v2.x) + bflo(v3.x));
        a1 += (bfhi(v0.x) + bfhi(v1.x)) + (bfhi(v2.x) + bfhi(v3.x));
        a2 += (bflo(v0.y) + bflo(v1.y)) + (bflo(v2.y) + bflo(v3.y));
        a3 += (bfhi(v0.y) + bfhi(v1.y)) + (bfhi(v2.y) + bfhi(v3.y));
        a4 += (bflo(v0.z) + bflo(v1.z)) + (bflo(v2.z) + bflo(v3.z));
        a5 += (bfhi(v0.z) + bfhi(v1.z)) + (bfhi(v2.z) + bfhi(v3.z));
        a6 += (bflo(v0.w) + bflo(v1.w)) + (bflo(v2.w) + bflo(v3.w));
        a7 += (bfhi(v0.w) + bfhi(v1.w)) + (bfhi(v2.w) + bfhi(v3.w));
    }
    for (; i < e; ++i) {
        uint4 v = x[(size_t)sl[i] * 16 + l16];
        a0 += bflo(v.x); a1 += bfhi(v.x);
        a2 += bflo(v.y); a3 += bfhi(v.y);
        a4 += bflo(v.z); a5 += bfhi(v.z);
        a6 += bflo(v.w); a7 += bfhi(v.w);
    }
    int d = e - s;
    float inv = 1.f / (float)(d > 0 ? d : 1);
    uint4 r;
    r.x = f2bf(a0 * inv) | (f2bf(a1 * inv) << 16);
    r.y = f2bf(a2 * inv) | (f2bf(a3 * inv) << 16);
    r.z = f2bf(a4 * inv) | (f2bf(a5 * inv) << 16);
    r.w = f2bf(a6 * inv) | (f2bf(a7 * inv) << 16);
    o[(size_t)row * 16 + l16] = r;
}

// ---------------- weight fusion ----------------
__global__ void fuseW(const float* __restrict__ Wn1, const float* __restrict__ Ws1,
                      const float* __restrict__ Wu1,
                      const float* __restrict__ Wn2, const float* __restrict__ Ws2,
                      const float* __restrict__ Wu2, ushort* __restrict__ FT) {
    int j5 = blockIdx.y;
    int l = j5 / 5, t = j5 - l * 5;
    const float* Wn = l ? Wn2 : Wn1;
    const float* Ws = l ? Ws2 : Ws1;
    const float* Wu = l ? Wu2 : Wu1;
    const float *A0, *B0, *A1 = nullptr, *B1 = nullptr;
    float al;
    switch (t) {
        case 0: A0 = Wn;          B0 = Wu;          al = 1.0f; break;
        case 1: A0 = Wn + 16384;  B0 = Wu + 32768;  al = 0.5f; break;
        case 2: A0 = Wn + 32768;  B0 = Wu + 65536;  al = 0.5f; break;
        case 3: A0 = Ws;          B0 = Wu + 16384;  al = 1.0f; break;
        default:
            A0 = Ws + 16384; B0 = Wu + 49152;
            A1 = Ws + 32768; B1 = Wu + 81920;
            al = 0.5f; break;
    }
    int i = blockIdx.x, j = threadIdx.x;
    float s0 = 0, s1 = 0, s2 = 0, s3 = 0;
    #pragma unroll 4
    for (int k = 0; k < 128; k += 4) {
        s0 += A0[i * 128 + k]     * B0[k * 128 + j];
        s1 += A0[i * 128 + k + 1] * B0[(k + 1) * 128 + j];
        s2 += A0[i * 128 + k + 2] * B0[(k + 2) * 128 + j];
        s3 += A0[i * 128 + k + 3] * B0[(k + 3) * 128 + j];
    }
    if (A1) {
        #pragma unroll 4
        for (int k = 0; k < 128; k += 4) {
            s0 += A1[i * 128 + k]     * B1[k * 128 + j];
            s1 += A1[i * 128 + k + 1] * B1[(k + 1) * 128 + j];
            s2 += A1[i * 128 + k + 2] * B1[(k + 2) * 128 + j];
            s3 += A1[i * 128 + k + 3] * B1[(k + 3) * 128 + j];
        }
    }
    float r = al * ((s0 + s1) + (s2 + s3));
    FT[(size_t)j5 * 16384 + j * 128 + i] = (ushort)f2bf(r);
}

__global__ void fuseB(const float* __restrict__ bn1, const float* __restrict__ bs1,
                      const float* __restrict__ bu1, const float* __restrict__ Wu1,
                      const float* __restrict__ bn2, const float* __restrict__ bs2,
                      const float* __restrict__ bu2, const float* __restrict__ Wu2,
                      float* __restrict__ FC) {
    int jb = blockIdx.x;
    int l = jb >> 1, which = jb & 1;
    const float* bn = l ? bn2 : bn1;
    const float* bs = l ? bs2 : bs1;
    const float* bu = l ? bu2 : bu1;
    const float* Wu = l ? Wu2 : Wu1;
    int j = threadIdx.x;
    float s = 0.f;
    if (which == 0) {
        s = bu[j];
        for (int k = 0; k < 128; ++k)
            s += bn[k] * Wu[k * 128 + j] + bs[k] * Wu[(128 + k) * 128 + j];
    } else {
        #pragma unroll
        for (int tt = 1; tt <= 2; ++tt) {
            const float* Wt = Wu + tt * 32768;
            float p = bu[tt * 128 + j];
            for (int k = 0; k < 128; ++k)
                p += bn[tt * 128 + k] * Wt[k * 128 + j] + bs[tt * 128 + k] * Wt[(128 + k) * 128 + j];
            s += 0.5f * p;
        }
    }
    FC[jb * 128 + j] = s;
}

// ---------------- batched MFMA GEMM: dbuf global_load_lds + LDS-transposed coalesced C store ----------------
__global__ __launch_bounds__(256) void gemm2_mfma(
    const ushort* __restrict__ Aq0, const ushort* __restrict__ Wq0,
    const ushort* __restrict__ Aq1, const ushort* __restrict__ Wq1,
    const ushort* __restrict__ Ap0, const ushort* __restrict__ Wp0,
    const ushort* __restrict__ Ap1, const ushort* __restrict__ Wp1,
    const ushort* __restrict__ Ap2, const ushort* __restrict__ Wp2,
    const float* __restrict__ biasq, const float* __restrict__ biasp,
    ushort* __restrict__ Cq, ushort* __restrict__ Cp, int M,
    float* __restrict__ STW) {
    __shared__ ushort As[2][64 * 128];
    int y = blockIdx.y;
    const float* bias = y ? biasp : biasq;
    ushort* C = y ? Cp : Cq;
    float* colsum = STW + (size_t)(blockIdx.x & 31) * 512 + (y ? 0 : 256);
    float* colsq = colsum + 128;

    int tid = threadIdx.x;
    int wid = tid >> 6;
    int lane = tid & 63;
    int l15 = lane & 15, lg = lane >> 4;
    int row0 = blockIdx.x * 64;
    int nIn = y ? 3 : 2;

    const ushort* Ax[3];
    const ushort* Wx[3];
    Ax[0] = y ? Ap0 : Aq0;  Wx[0] = y ? Wp0 : Wq0;
    Ax[1] = y ? Ap1 : Aq1;  Wx[1] = y ? Wp1 : Wq1;
    Ax[2] = Ap2;            Wx[2] = Wp2;

    auto stage = [&](const ushort* A, ushort* buf) {
        #pragma unroll
        for (int p = 0; p < 4; ++p) {
            int row = wid * 16 + p * 4 + (lane >> 4);
            int gr = row0 + row;
            if (gr > M - 1) gr = M - 1;
            const ushort* src = A + (size_t)gr * 128 + (((lane & 15) ^ (row & 7)) * 8);
            gload16(src, buf + (wid * 4 + p) * 512);
        }
    };

    f32x4 acc[4][2];
    #pragma unroll
    for (int rb = 0; rb < 4; ++rb)
        #pragma unroll
        for (int cb = 0; cb < 2; ++cb) acc[rb][cb] = (f32x4){0.f, 0.f, 0.f, 0.f};

    stage(Ax[0], As[0]);
    __syncthreads();
    int cur = 0;

    #pragma unroll
    for (int inp = 0; inp < 3; ++inp) {
        if (inp == 2 && nIn == 2) break;   // wave-uniform
        const ushort* W = Wx[inp];
        short8 bw[4][2];
        #pragma unroll
        for (int k0 = 0; k0 < 4; ++k0)
            #pragma unroll
            for (int cb = 0; cb < 2; ++cb)
                bw[k0][cb] = *(const short8*)(W + (size_t)(wid * 32 + cb * 16 + l15) * 128 + k0 * 32 + lg * 8);
        if (inp + 1 < nIn) stage(Ax[inp + 1], As[cur ^ 1]);
        #pragma unroll
        for (int k0 = 0; k0 < 4; ++k0) {
            short8 a[4];
            #pragma unroll
            for (int rb = 0; rb < 4; ++rb)
                a[rb] = *(const short8*)&As[cur][(rb * 16 + l15) * 128 + (((k0 * 4 + lg) ^ (l15 & 7)) * 8)];
            #pragma unroll
            for (int rb = 0; rb < 4; ++rb)
                #pragma unroll
                for (int cb = 0; cb < 2; ++cb)
                    acc[rb][cb] = __builtin_amdgcn_mfma_f32_16x16x32_bf16(a[rb], bw[k0][cb], acc[rb][cb], 0, 0, 0);
        }
        __syncthreads();             // also frees As for the epilogue transpose
        cur ^= 1;
    }

    // epilogue: bias + BN stats (regs) + bf16 pack into LDS[row][col]
    float ps[2] = {0.f, 0.f}, pq[2] = {0.f, 0.f};
    int colbase = wid * 32;
    ushort* T = As[0];
    #pragma unroll
    for (int cb = 0; cb < 2; ++cb) {
        int col = colbase + cb * 16 + l15;
        float b = bias[col];
        #pragma unroll
        for (int rb = 0; rb < 4; ++rb) {
            int lrow = rb * 16 + lg * 4;
            #pragma unroll
            for (int i = 0; i < 4; ++i) {
                float v = acc[rb][cb][i] + b;
                T[(lrow + i) * 128 + col] = (ushort)f2bf(v);
                if (row0 + lrow + i < M) {
                    ps[cb] += v;
                    pq[cb] += v * v;
                }
            }
        }
    }
    #pragma unroll
    for (int cb = 0; cb < 2; ++cb) {
        ps[cb] += __shfl_xor(ps[cb], 16, 64);
        ps[cb] += __shfl_xor(ps[cb], 32, 64);
        pq[cb] += __shfl_xor(pq[cb], 16, 64);
        pq[cb] += __shfl_xor(pq[cb], 32, 64);
    }
    if (lane < 16) {
        atomicAdd(&colsum[colbase + lane], ps[0]);
        atomicAdd(&colsq[colbase + lane], pq[0]);
        atomicAdd(&colsum[colbase + 16 + lane], ps[1]);
        atomicAdd(&colsq[colbase + 16 + lane], pq[1]);
    }
    __syncthreads();
    // coalesced C store: thread -> row tid>>2, 32-col chunk (tid&3)*32 (64B = 4x uint4)
    {
        int row = tid >> 2;
        int c0 = (tid & 3) * 32;
        int gr = row0 + row;
        if (gr < M) {
            uint4* dst = (uint4*)(C + (size_t)gr * 128 + c0);
            const uint4* src4 = (const uint4*)&T[row * 128 + c0];
            dst[0] = src4[0];
            dst[1] = src4[1];
            dst[2] = src4[2];
            dst[3] = src4[3];
        }
    }
}

// ---------------- BN finalize: reduce 32 shadow copies, self-zero for next layer ----------------
__global__ void bn_fin2(float* __restrict__ STW, float* __restrict__ ST,
                        const float* __restrict__ g0, const float* __restrict__ b0,
                        const float* __restrict__ g1, const float* __restrict__ b1, int N) {
    int tid = threadIdx.x;
    int which = tid >> 7, c = tid & 127;
    float s = 0.f, q = 0.f;
    #pragma unroll 8
    for (int cp = 0; cp < 32; ++cp) {
        s += STW[(size_t)cp * 512 + which * 256 + c];
        q += STW[(size_t)cp * 512 + which * 256 + 128 + c];
    }
    #pragma unroll 8
    for (int cp = 0; cp < 32; ++cp) {
        STW[(size_t)cp * 512 + which * 256 + c] = 0.f;
        STW[(size_t)cp * 512 + which * 256 + 128 + c] = 0.f;
    }
    const float* g = which ? g1 : g0;
    const float* b = which ? b1 : b0;
    float m = s / (float)N;
    float v = q / (float)N - m * m;
    float rs = rsqrtf(v + 1e-5f);
    float sc = g[c] * rs;
    ST[512 + which * 256 + c] = sc;
    ST[640 + which * 256 + c] = b[c] - m * sc;
}

// ---------------- BN apply + LeakyReLU: bf16 in -> bf16 out (layer 1 only) ----------------
__global__ void bn_apply2(const ushort* __restrict__ Cp, ushort* __restrict__ X0b,
                          const ushort* __restrict__ Cq, ushort* __restrict__ X1b,
                          const float* __restrict__ ST, int n4) {
    int y = blockIdx.y;
    const uint2* in = (const uint2*)(y ? Cq : Cp);
    uint2* out = (uint2*)(y ? X1b : X0b);
    const float* sc = ST + 512 + y * 256;
    const float* sh = sc + 128;
    int i = blockIdx.x * blockDim.x + threadIdx.x;
    int stride = gridDim.x * blockDim.x;
    for (; i < n4; i += stride) {
        uint2 v = in[i];
        int cb = (i * 4) & 127;
        float4 s4 = *(const float4*)&sc[cb];
        float4 h4 = *(const float4*)&sh[cb];
        float y0 = bflo(v.x) * s4.x + h4.x;
        float y1 = bfhi(v.x) * s4.y + h4.y;
        float y2 = bflo(v.y) * s4.z + h4.z;
        float y3 = bfhi(v.y) * s4.w + h4.w;
        y0 = (y0 >= 0.f) ? y0 : 0.01f * y0;
        y1 = (y1 >= 0.f) ? y1 : 0.01f * y1;
        y2 = (y2 >= 0.f) ? y2 : 0.01f * y2;
        y3 = (y3 >= 0.f) ? y3 : 0.01f * y3;
        uint2 o;
        o.x = f2bf(y0) | (f2bf(y1) << 16);
        o.y = f2bf(y2) | (f2bf(y3) << 16);
        out[i] = o;
    }
}

// ---------------- fused BN + LeakyReLU + projection (layer 2), both types ----------------
__global__ void projbn2(const ushort* __restrict__ Cp, const ushort* __restrict__ Cq,
                        const float* __restrict__ ST,
                        const float* __restrict__ Wp, const float* __restrict__ bp,
                        float* __restrict__ out, int N) {
    int y = blockIdx.y;
    const uint* h = (const uint*)(y ? Cq : Cp);
    const float* W = Wp + y * 1024;
    const float* b = bp + y * 8;
    float* op = out + (size_t)y * N * 8;
    __shared__ float Wsh[1024];
    __shared__ float scs[128], shs[128];
    __shared__ float bsh[8];
    int tid = threadIdx.x;
    for (int i = tid; i < 1024; i += 256) Wsh[i] = W[i];
    if (tid < 128) {
        scs[tid] = ST[512 + y * 256 + tid];
        shs[tid] = ST[640 + y * 256 + tid];
    }
    if (tid < 8) bsh[tid] = b[tid];
    __syncthreads();
    int idx = blockIdx.x * 256 + tid;
    if (idx >= N * LBL) return;
    int r = idx >> 3, c = idx & 7;
    const uint* hr = h + (size_t)r * 64;
    float s = bsh[c];
    #pragma unroll
    for (int k2 = 0; k2 < 64; ++k2) {
        uint v = hr[k2];
        float xa = bflo(v) * scs[2 * k2] + shs[2 * k2];
        float xb = bfhi(v) * scs[2 * k2 + 1] + shs[2 * k2 + 1];
        xa = (xa >= 0.f) ? xa : 0.01f * xa;
        xb = (xb >= 0.f) ? xb : 0.01f * xb;
        s += xa * Wsh[(2 * k2) * 8 + c] + xb * Wsh[(2 * k2 + 1) * 8 + c];
    }
    op[idx] = s;
}

// ---------------- host ----------------

extern "C" void kernel_launch(void* const* d_in, const int* in_sizes, int n_in,
                              void* d_out, int out_size, void* d_ws, size_t ws_size,
                              hipStream_t stream) {
    const float* x0 = (const float*)d_in[0];
    const float* x1 = (const float*)d_in[1];
    const float* Wn1 = (const float*)d_in[2];
    const float* Ws1 = (const float*)d_in[3];
    const float* Wu1 = (const float*)d_in[4];
    const float* Wn2 = (const float*)d_in[5];
    const float* Ws2 = (const float*)d_in[6];
    const float* Wu2 = (const float*)d_in[7];
    const float* bnn[2] = {(const float*)d_in[8], (const float*)d_in[11]};
    const float* bss[2] = {(const float*)d_in[9], (const float*)d_in[12]};
    const float* buu[2] = {(const float*)d_in[10], (const float*)d_in[13]};
    const float* gam[2] = {(const float*)d_in[14], (const float*)d_in[16]};
    const float* bet[2] = {(const float*)d_in[15], (const float*)d_in[17]};
    const float* Wp = (const float*)d_in[18];
    const float* bp = (const float*)d_in[19];
    const int* ei[3] = {(const int*)d_in[20], (const int*)d_in[21], (const int*)d_in[22]};

    const int N = in_sizes[0] / 128;
    const int E = in_sizes[20] / 2;
    const int NB = (N + (1 << BSH) - 1) >> BSH;
    float* out = (float*)d_out;

    char* wp_ = (char*)d_ws;
    auto carve = [&](size_t bytes) {
        char* r = wp_;
        wp_ += (bytes + 255) & ~(size_t)255;
        return r;
    };
    size_t nodeB = (size_t)N * 128 * sizeof(ushort);
    ushort* Cp = (ushort*)carve(nodeB);   // h0pre bf16 (pairs aliases this early)
    ushort* Cq = (ushort*)carve(nodeB);   // h1pre bf16
    ushort* Pb = (ushort*)carve(nodeB);
    ushort* Rb = (ushort*)carve(nodeB);
    ushort* Sb = (ushort*)carve(nodeB);
    ushort* X0b = (ushort*)carve(nodeB);
    ushort* X1b = (ushort*)carve(nodeB);
    ushort* x0b = (ushort*)carve(nodeB);
    ushort* x1b = (ushort*)carve(nodeB);
    ushort* FT = (ushort*)carve(10 * 16384 * 2);
    float* FC = (float*)carve(4 * 128 * 4);
    float* ST = (float*)carve(1024 * 4);           // scale/shift region
    float* STW = (float*)carve(32 * 512 * 4);      // 32 shadow BN-stat copies
    int* offs = (int*)carve((size_t)3 * (N + 1) * 4);
    ushort* srcs = (ushort*)carve((size_t)3 * E * 2);
    int* bcnt = (int*)carve((size_t)3 * NB * 4);
    int* bso = (int*)carve((size_t)3 * (NB + 1) * 4);
    int* gcur = (int*)carve((size_t)3 * NB * 4);
    uint* pairs = (uint*)Cp;  // 3*E*4 = 6 MB <= nodeB (12.8 MB); dead before gemm writes Cp

    const int ag = (N + 15) / 16;
    const int gg = (N + 63) / 64;
    const int pg = (N * LBL + 255) / 256;
    const int bg = (E + 256 * BIN_CH - 1) / (256 * BIN_CH);

    f2b2<<<dim3(1024, 2), 256, 0, stream>>>((const float4*)x0, (const float4*)x1,
                                            (uint2*)x0b, (uint2*)x1b, N * 32);

    hipMemsetAsync(bcnt, 0, (size_t)3 * NB * 4, stream);
    hipMemsetAsync(STW, 0, 32 * 512 * 4, stream);
    bhist3<<<dim3(512, 3), 256, 0, stream>>>(ei[0], ei[1], ei[2], E, NB, bcnt);
    bscan<<<1, 64, 0, stream>>>(bcnt, bso, gcur, NB);
    bin3<<<dim3(bg, 3), 256, 0, stream>>>(ei[0], ei[1], ei[2], E, NB, gcur, pairs);
    csr3<<<dim3(NB, 3), 256, 0, stream>>>(pairs, bso, E, N, NB, offs, srcs);

    fuseW<<<dim3(128, 10), 128, 0, stream>>>(Wn1, Ws1, Wu1, Wn2, Ws2, Wu2, FT);
    fuseB<<<4, 128, 0, stream>>>(bnn[0], bss[0], buu[0], Wu1, bnn[1], bss[1], buu[1], Wu2, FC);

    const ushort* srcS[2][3] = {{x0b, x1b, x0b}, {X0b, X1b, X0b}};
    const ushort* dstX[2][2] = {{x0b, x1b}, {X0b, X1b}};

    for (int l = 0; l < 2; ++l) {
        const ushort* FA0T = FT + (size_t)(l * 5 + 0) * 16384;
        const ushort* FA1T = FT + (size_t)(l * 5 + 1) * 16384;
        const ushort* FA2T = FT + (size_t)(l * 5 + 2) * 16384;
        const ushort* FB1T = FT + (size_t)(l * 5 + 3) * 16384;
        const ushort* FB0T = FT + (size_t)(l * 5 + 4) * 16384;
        const float* fcH1 = FC + (l * 2 + 0) * 128;
        const float* fcH0 = FC + (l * 2 + 1) * 128;

        agg3<<<dim3(ag, 3), 256, 0, stream>>>(srcS[l][0], srcS[l][1], srcS[l][2],
                                              (uint*)Pb, (uint*)Rb, (uint*)Sb,
                                              offs, srcs, N, E);

        // y=0: Cq = Pb@FA0 + x1@FB1 ; y=1: Cp = Rb@FA1 + Sb@FA2 + x0@FB0
        gemm2_mfma<<<dim3(gg, 2), 256, 0, stream>>>(
            Pb, FA0T, dstX[l][1], FB1T,
            Rb, FA1T, Sb, FA2T, dstX[l][0], FB0T,
            fcH1, fcH0, Cq, Cp, N, STW);

        bn_fin2<<<1, 256, 0, stream>>>(STW, ST, gam[l], bet[l], gam[l] + 128, bet[l] + 128, N);
        if (l == 0)
            bn_apply2<<<dim3(1024, 2), 256, 0, stream>>>(Cp, X0b, Cq, X1b, ST, N * 32);
    }

    // layer-2 BN + LeakyReLU fused into the projection
    projbn2<<<dim3(pg, 2), 256, 0, stream>>>(Cp, Cq, ST, Wp, bp, out, N);
}

// Round 15
// 285.719 us; speedup vs baseline: 1.1396x; 1.0476x over previous
//
#include <hip/hip_runtime.h>

#define LBL 8
#define NBMAX 128
#define BSH 9            // 512 dsts per bucket
#define BCAP 8192        // LDS sort capacity per bucket (mean ~5100)

typedef __attribute__((ext_vector_type(8))) short short8;
typedef __attribute__((ext_vector_type(4))) float f32x4;

__device__ __forceinline__ uint f2bf(float x) {
    uint u = __float_as_uint(x);
    return (u + 0x7fffu + ((u >> 16) & 1u)) >> 16;
}
__device__ __forceinline__ float bflo(uint v) { return __uint_as_float(v << 16); }
__device__ __forceinline__ float bfhi(uint v) { return __uint_as_float(v & 0xffff0000u); }

// async global->LDS 16B per lane: dest = lds_base(wave-uniform) + lane*16
__device__ __forceinline__ void gload16(const ushort* g, ushort* l) {
    __builtin_amdgcn_global_load_lds((const __attribute__((address_space(1))) uint*)g,
                                     (__attribute__((address_space(3))) uint*)l, 16, 0, 0);
}

// ---------------- PREP: f2b (x2) + bucket hist (x3) + weight fusion, one dispatch ----------------
// block ranges: [0,1024) f2b | [1024,2560) bhist | [2560,3200) fuseW | [3200,3202) fuseB
__global__ __launch_bounds__(256) void prep(
    const float4* __restrict__ x0, const float4* __restrict__ x1,
    uint2* __restrict__ o0, uint2* __restrict__ o1, int n4,
    const int* __restrict__ e0, const int* __restrict__ e1, const int* __restrict__ e2,
    int E, int NB, int* __restrict__ bcnt,
    const float* __restrict__ Wn1, const float* __restrict__ Ws1, const float* __restrict__ Wu1,
    const float* __restrict__ Wn2, const float* __restrict__ Ws2, const float* __restrict__ Wu2,
    ushort* __restrict__ FT,
    const float* __restrict__ bn1, const float* __restrict__ bs1, const float* __restrict__ bu1,
    const float* __restrict__ bn2, const float* __restrict__ bs2, const float* __restrict__ bu2,
    float* __restrict__ FC) {
    __shared__ int h[NBMAX];
    int b = blockIdx.x;
    int tid = threadIdx.x;

    if (b < 1024) {                       // ---- fp32 -> bf16 ----
        int y = b >> 9;
        const float4* in = y ? x1 : x0;
        uint2* out = y ? o1 : o0;
        int i = (b & 511) * 256 + tid;
        int stride = 512 * 256;
        for (; i < n4; i += stride) {
            float4 v = in[i];
            uint2 o;
            o.x = f2bf(v.x) | (f2bf(v.y) << 16);
            o.y = f2bf(v.z) | (f2bf(v.w) << 16);
            out[i] = o;
        }
    } else if (b < 2560) {                // ---- coarse bucket histogram ----
        int bb = b - 1024;
        int m = bb / 512, sub = bb - m * 512;
        const int* dst = (m == 0 ? e0 : (m == 1 ? e1 : e2)) + E;
        if (tid < NB) h[tid] = 0;
        __syncthreads();
        int i = sub * 256 + tid, st = 512 * 256;
        for (; i < E; i += st) atomicAdd(&h[dst[i] >> BSH], 1);
        __syncthreads();
        if (tid < NB && h[tid]) atomicAdd(&bcnt[m * NB + tid], h[tid]);
    } else if (b < 3200) {                // ---- fuseW: 64 blocks per j5, 2 rows per block ----
        int bb = b - 2560;
        int j5 = bb >> 6, rem = bb & 63;
        int l = j5 / 5, t = j5 - l * 5;
        const float* Wn = l ? Wn2 : Wn1;
        const float* Ws = l ? Ws2 : Ws1;
        const float* Wu = l ? Wu2 : Wu1;
        const float *A0, *B0, *A1 = nullptr, *B1 = nullptr;
        float al;
        switch (t) {
            case 0: A0 = Wn;          B0 = Wu;          al = 1.0f; break;
            case 1: A0 = Wn + 16384;  B0 = Wu + 32768;  al = 0.5f; break;
            case 2: A0 = Wn + 32768;  B0 = Wu + 65536;  al = 0.5f; break;
            case 3: A0 = Ws;          B0 = Wu + 16384;  al = 1.0f; break;
            default:
                A0 = Ws + 16384; B0 = Wu + 49152;
                A1 = Ws + 32768; B1 = Wu + 81920;
                al = 0.5f; break;
        }
        int i = rem * 2 + (tid >> 7);
        int j = tid & 127;
        float s0 = 0, s1 = 0, s2 = 0, s3 = 0;
        #pragma unroll 4
        for (int k = 0; k < 128; k += 4) {
            s0 += A0[i * 128 + k]     * B0[k * 128 + j];
            s1 += A0[i * 128 + k + 1] * B0[(k + 1) * 128 + j];
            s2 += A0[i * 128 + k + 2] * B0[(k + 2) * 128 + j];
            s3 += A0[i * 128 + k + 3] * B0[(k + 3) * 128 + j];
        }
        if (A1) {
            #pragma unroll 4
            for (int k = 0; k < 128; k += 4) {
                s0 += A1[i * 128 + k]     * B1[k * 128 + j];
                s1 += A1[i * 128 + k + 1] * B1[(k + 1) * 128 + j];
                s2 += A1[i * 128 + k + 2] * B1[(k + 2) * 128 + j];
                s3 += A1[i * 128 + k + 3] * B1[(k + 3) * 128 + j];
            }
        }
        float r = al * ((s0 + s1) + (s2 + s3));
        FT[(size_t)j5 * 16384 + j * 128 + i] = (ushort)f2bf(r);
    } else {                              // ---- fuseB: 2 jobs per block ----
        int jb = (b - 3200) * 2 + (tid >> 7);
        int l = jb >> 1, which = jb & 1;
        const float* bn = l ? bn2 : bn1;
        const float* bs = l ? bs2 : bs1;
        const float* bu = l ? bu2 : bu1;
        const float* Wu = l ? Wu2 : Wu1;
        int j = tid & 127;
        float s = 0.f;
        if (which == 0) {
            s = bu[j];
            for (int k = 0; k < 128; ++k)
                s += bn[k] * Wu[k * 128 + j] + bs[k] * Wu[(128 + k) * 128 + j];
        } else {
            #pragma unroll
            for (int tt = 1; tt <= 2; ++tt) {
                const float* Wt = Wu + tt * 32768;
                float p = bu[tt * 128 + j];
                for (int k = 0; k < 128; ++k)
                    p += bn[tt * 128 + k] * Wt[k * 128 + j] + bs[tt * 128 + k] * Wt[(128 + k) * 128 + j];
                s += 0.5f * p;
            }
        }
        FC[jb * 128 + j] = s;
    }
}

// ---------------- CSR build (scan + bin + fine sort) ----------------
__global__ void bscan(const int* __restrict__ bcnt, int* __restrict__ bso,
                      int* __restrict__ gcur, int NB) {
    int m = threadIdx.x;
    if (m >= 3) return;
    int acc = 0;
    for (int b = 0; b < NB; ++b) {
        bso[m * (NB + 1) + b] = acc;
        gcur[m * NB + b] = acc;
        acc += bcnt[m * NB + b];
    }
    bso[m * (NB + 1) + NB] = acc;
}

// record: src (16b) | dst-low-9 << 16   (requires N <= 65536)
#define BIN_CH 16
__global__ __launch_bounds__(256) void bin3(const int* __restrict__ e0, const int* __restrict__ e1,
                                            const int* __restrict__ e2, int E, int NB,
                                            int* __restrict__ gcur, uint* __restrict__ pairs) {
    int m = blockIdx.y;
    const int* eb = (m == 0 ? e0 : (m == 1 ? e1 : e2));
    const int* src = eb;
    const int* dst = eb + E;
    uint* pp = pairs + (size_t)m * E;
    int* gc = gcur + m * NB;
    __shared__ int h[NBMAX], base[NBMAX], pos[NBMAX];
    int tid = threadIdx.x;
    if (tid < NB) { h[tid] = 0; pos[tid] = 0; }
    __syncthreads();
    int i0 = blockIdx.x * (256 * BIN_CH);
    uint pk[BIN_CH];
    int bk[BIN_CH];
    #pragma unroll
    for (int u = 0; u < BIN_CH; ++u) {
        int i = i0 + u * 256 + tid;
        bk[u] = -1;
        if (i < E) {
            int s = src[i], d = dst[i];
            bk[u] = d >> BSH;
            pk[u] = (uint)s | ((uint)(d & ((1 << BSH) - 1)) << 16);
            atomicAdd(&h[bk[u]], 1);
        }
    }
    __syncthreads();
    if (tid < NB && h[tid]) base[tid] = atomicAdd(&gc[tid], h[tid]);
    __syncthreads();
    #pragma unroll
    for (int u = 0; u < BIN_CH; ++u) {
        if (bk[u] >= 0) {
            int p = base[bk[u]] + atomicAdd(&pos[bk[u]], 1);
            pp[p] = pk[u];
        }
    }
}

__global__ __launch_bounds__(256) void csr3(const uint* __restrict__ pairs, const int* __restrict__ bso,
                                            int E, int N, int NB,
                                            int* __restrict__ offs, ushort* __restrict__ srcs) {
    int m = blockIdx.y, b = blockIdx.x;
    const uint* pp = pairs + (size_t)m * E;
    int gstart = bso[m * (NB + 1) + b];
    int gend = bso[m * (NB + 1) + b + 1];
    int cnt = gend - gstart;
    if (cnt > BCAP) cnt = BCAP;
    int d0 = b << BSH;
    int dcnt = N - d0;
    if (dcnt > (1 << BSH)) dcnt = 1 << BSH;

    __shared__ int hist[1 << BSH], po[1 << BSH], off0[1 << BSH];
    __shared__ int lsort[BCAP];
    __shared__ int wsum[4];
    int tid = threadIdx.x;
    hist[tid] = 0;
    hist[tid + 256] = 0;
    __syncthreads();
    for (int i = tid; i < cnt; i += 256) atomicAdd(&hist[pp[gstart + i] >> 16], 1);
    __syncthreads();
    int a = hist[2 * tid], b2 = hist[2 * tid + 1];
    int s = a + b2;
    int lane = tid & 63, w = tid >> 6;
    #pragma unroll
    for (int o = 1; o < 64; o <<= 1) {
        int v = __shfl_up(s, o, 64);
        if (lane >= o) s += v;
    }
    if (lane == 63) wsum[w] = s;
    __syncthreads();
    int wp = 0;
    #pragma unroll
    for (int q = 0; q < 4; ++q)
        if (q < w) wp += wsum[q];
    int excl = wp + s - a - b2;
    off0[2 * tid] = excl; off0[2 * tid + 1] = excl + a;
    po[2 * tid] = excl;   po[2 * tid + 1] = excl + a;
    __syncthreads();
    for (int j = tid; j < dcnt; j += 256) offs[(size_t)m * (N + 1) + d0 + j] = gstart + off0[j];
    if (b == NB - 1 && tid == 0) offs[(size_t)m * (N + 1) + N] = bso[m * (NB + 1) + NB];
    for (int i = tid; i < cnt; i += 256) {
        uint e = pp[gstart + i];
        int p = atomicAdd(&po[e >> 16], 1);
        if (p < BCAP) lsort[p] = (int)(e & 0xffffu);
    }
    __syncthreads();
    for (int i = tid; i < cnt; i += 256) srcs[(size_t)m * E + gstart + i] = (ushort)lsort[i];
}

// ---------------- segment mean: 4 rows/wave (16 lanes x uint4 = 256B row), 4-unrolled ----------------
__global__ void agg3(const ushort* __restrict__ s0, const ushort* __restrict__ s1,
                     const ushort* __restrict__ s2,
                     uint* __restrict__ o0, uint* __restrict__ o1, uint* __restrict__ o2,
                     const int* __restrict__ offs, const ushort* __restrict__ srcs,
                     int n, int E) {
    int m = blockIdx.y;
    const uint4* x = (const uint4*)(m == 0 ? s0 : (m == 1 ? s1 : s2));
    uint4* o = (uint4*)(m == 0 ? o0 : (m == 1 ? o1 : o2));
    const int* off = offs + (size_t)m * (n + 1);
    const ushort* sl = srcs + (size_t)m * E;

    int tid = threadIdx.x;
    int l16 = tid & 15;
    int row = blockIdx.x * 16 + (tid >> 4);
    if (row >= n) return;
    int s = off[row], e = off[row + 1];
    float a0 = 0, a1 = 0, a2 = 0, a3 = 0, a4 = 0, a5 = 0, a6 = 0, a7 = 0;
    int i = s;
    for (; i + 3 < e; i += 4) {
        int j0 = sl[i], j1 = sl[i + 1], j2 = sl[i + 2], j3 = sl[i + 3];
        uint4 v0 = x[(size_t)j0 * 16 + l16];
        uint4 v1 = x[(size_t)j1 * 16 + l16];
        uint4 v2 = x[(size_t)j2 * 16 + l16];
        uint4 v3 = x[(size_t)j3 * 16 + l16];
        a0 += (bflo(v0.x) + bflo(v1.x)) + (bflo(v2.x) + bflo(v3.x));
        a1 += (bfhi(v0.x) + bfhi(v1.x)) + (bfhi(v2.x) + bfhi(v3.x));
        a2 += (bflo(v0.y) + bflo(v1.y)) + (bflo(v2.y) + bflo(v3.y));
        a3 += (bfhi(v0.y) + bfhi(v1.y)) + (bfhi(v2.y) + bfhi(v3.y));
        a4 += (bflo(v0.z) + bflo(v1.z)) + (bflo(v2.z) + bflo(v3.z));
        a5 += (bfhi(v0.z) + bfhi(v1.z)) + (bfhi(v2.z) + bfhi(v3.z));
        a6 += (bflo(v0.w) + bflo(v1.w)) + (bflo(v2.w) + bflo(v3.w));
        a7 += (bfhi(v0.w) + bfhi(v1.w)) + (bfhi(v2.w) + bfhi(v3.w));
    }
    for (; i < e; ++i) {
        uint4 v = x[(size_t)sl[i] * 16 + l16];
        a0 += bflo(v.x); a1 += bfhi(v.x);
        a2 += bflo(v.y); a3 += bfhi(v.y);
        a4 += bflo(v.z); a5 += bfhi(v.z);
        a6 += bflo(v.w); a7 += bfhi(v.w);
    }
    int d = e - s;
    float inv = 1.f / (float)(d > 0 ? d : 1);
    uint4 r;
    r.x = f2bf(a0 * inv) | (f2bf(a1 * inv) << 16);
    r.y = f2bf(a2 * inv) | (f2bf(a3 * inv) << 16);
    r.z = f2bf(a4 * inv) | (f2bf(a5 * inv) << 16);
    r.w = f2bf(a6 * inv) | (f2bf(a7 * inv) << 16);
    o[(size_t)row * 16 + l16] = r;
}

// ---------------- batched MFMA GEMM: dbuf global_load_lds + LDS-transposed coalesced C store ----------------
__global__ __launch_bounds__(256) void gemm2_mfma(
    const ushort* __restrict__ Aq0, const ushort* __restrict__ Wq0,
    const ushort* __restrict__ Aq1, const ushort* __restrict__ Wq1,
    const ushort* __restrict__ Ap0, const ushort* __restrict__ Wp0,
    const ushort* __restrict__ Ap1, const ushort* __restrict__ Wp1,
    const ushort* __restrict__ Ap2, const ushort* __restrict__ Wp2,
    const float* __restrict__ biasq, const float* __restrict__ biasp,
    ushort* __restrict__ Cq, ushort* __restrict__ Cp, int M,
    float* __restrict__ STW) {
    __shared__ ushort As[2][64 * 128];
    int y = blockIdx.y;
    const float* bias = y ? biasp : biasq;
    ushort* C = y ? Cp : Cq;
    float* colsum = STW + (size_t)(blockIdx.x & 31) * 512 + (y ? 0 : 256);
    float* colsq = colsum + 128;

    int tid = threadIdx.x;
    int wid = tid >> 6;
    int lane = tid & 63;
    int l15 = lane & 15, lg = lane >> 4;
    int row0 = blockIdx.x * 64;
    int nIn = y ? 3 : 2;

    const ushort* Ax[3];
    const ushort* Wx[3];
    Ax[0] = y ? Ap0 : Aq0;  Wx[0] = y ? Wp0 : Wq0;
    Ax[1] = y ? Ap1 : Aq1;  Wx[1] = y ? Wp1 : Wq1;
    Ax[2] = Ap2;            Wx[2] = Wp2;

    auto stage = [&](const ushort* A, ushort* buf) {
        #pragma unroll
        for (int p = 0; p < 4; ++p) {
            int row = wid * 16 + p * 4 + (lane >> 4);
            int gr = row0 + row;
            if (gr > M - 1) gr = M - 1;
            const ushort* src = A + (size_t)gr * 128 + (((lane & 15) ^ (row & 7)) * 8);
            gload16(src, buf + (wid * 4 + p) * 512);
        }
    };

    f32x4 acc[4][2];
    #pragma unroll
    for (int rb = 0; rb < 4; ++rb)
        #pragma unroll
        for (int cb = 0; cb < 2; ++cb) acc[rb][cb] = (f32x4){0.f, 0.f, 0.f, 0.f};

    stage(Ax[0], As[0]);
    __syncthreads();
    int cur = 0;

    #pragma unroll
    for (int inp = 0; inp < 3; ++inp) {
        if (inp == 2 && nIn == 2) break;   // wave-uniform
        const ushort* W = Wx[inp];
        short8 bw[4][2];
        #pragma unroll
        for (int k0 = 0; k0 < 4; ++k0)
            #pragma unroll
            for (int cb = 0; cb < 2; ++cb)
                bw[k0][cb] = *(const short8*)(W + (size_t)(wid * 32 + cb * 16 + l15) * 128 + k0 * 32 + lg * 8);
        if (inp + 1 < nIn) stage(Ax[inp + 1], As[cur ^ 1]);
        #pragma unroll
        for (int k0 = 0; k0 < 4; ++k0) {
            short8 a[4];
            #pragma unroll
            for (int rb = 0; rb < 4; ++rb)
                a[rb] = *(const short8*)&As[cur][(rb * 16 + l15) * 128 + (((k0 * 4 + lg) ^ (l15 & 7)) * 8)];
            #pragma unroll
            for (int rb = 0; rb < 4; ++rb)
                #pragma unroll
                for (int cb = 0; cb < 2; ++cb)
                    acc[rb][cb] = __builtin_amdgcn_mfma_f32_16x16x32_bf16(a[rb], bw[k0][cb], acc[rb][cb], 0, 0, 0);
        }
        __syncthreads();             // also frees As for the epilogue transpose
        cur ^= 1;
    }

    // epilogue: bias + BN stats (regs) + bf16 pack into LDS[row][col]
    float ps[2] = {0.f, 0.f}, pq[2] = {0.f, 0.f};
    int colbase = wid * 32;
    ushort* T = As[0];
    #pragma unroll
    for (int cb = 0; cb < 2; ++cb) {
        int col = colbase + cb * 16 + l15;
        float b = bias[col];
        #pragma unroll
        for (int rb = 0; rb < 4; ++rb) {
            int lrow = rb * 16 + lg * 4;
            #pragma unroll
            for (int i = 0; i < 4; ++i) {
                float v = acc[rb][cb][i] + b;
                T[(lrow + i) * 128 + col] = (ushort)f2bf(v);
                if (row0 + lrow + i < M) {
                    ps[cb] += v;
                    pq[cb] += v * v;
                }
            }
        }
    }
    #pragma unroll
    for (int cb = 0; cb < 2; ++cb) {
        ps[cb] += __shfl_xor(ps[cb], 16, 64);
        ps[cb] += __shfl_xor(ps[cb], 32, 64);
        pq[cb] += __shfl_xor(pq[cb], 16, 64);
        pq[cb] += __shfl_xor(pq[cb], 32, 64);
    }
    if (lane < 16) {
        atomicAdd(&colsum[colbase + lane], ps[0]);
        atomicAdd(&colsq[colbase + lane], pq[0]);
        atomicAdd(&colsum[colbase + 16 + lane], ps[1]);
        atomicAdd(&colsq[colbase + 16 + lane], pq[1]);
    }
    __syncthreads();
    // coalesced C store: thread -> row tid>>2, 32-col chunk (tid&3)*32
    {
        int row = tid >> 2;
        int c0 = (tid & 3) * 32;
        int gr = row0 + row;
        if (gr < M) {
            uint4* dst = (uint4*)(C + (size_t)gr * 128 + c0);
            const uint4* src4 = (const uint4*)&T[row * 128 + c0];
            dst[0] = src4[0];
            dst[1] = src4[1];
            dst[2] = src4[2];
            dst[3] = src4[3];
        }
    }
}

// ---------------- BN apply + LeakyReLU with in-block stat finalize (layer 1) ----------------
// STWl: this layer's 32 shadow copies. y=0: Cp->X0b uses offset 0, gamma g0; y=1: Cq->X1b offset 256.
__global__ void bn_apply2(const ushort* __restrict__ Cp, ushort* __restrict__ X0b,
                          const ushort* __restrict__ Cq, ushort* __restrict__ X1b,
                          const float* __restrict__ STWl,
                          const float* __restrict__ gam, const float* __restrict__ bet,
                          int N, int n4) {
    int y = blockIdx.y;
    const uint2* in = (const uint2*)(y ? Cq : Cp);
    uint2* out = (uint2*)(y ? X1b : X0b);
    __shared__ float scs[128], shs[128];
    int tid = threadIdx.x;
    if (tid < 128) {
        const float* base = STWl + (y ? 256 : 0);
        float s = 0.f, q = 0.f;
        #pragma unroll 8
        for (int cp = 0; cp < 32; ++cp) {
            s += base[cp * 512 + tid];
            q += base[cp * 512 + 128 + tid];
        }
        float m = s / (float)N;
        float v = q / (float)N - m * m;
        float rs = rsqrtf(v + 1e-5f);
        float sc = gam[y * 128 + tid] * rs;
        scs[tid] = sc;
        shs[tid] = bet[y * 128 + tid] - m * sc;
    }
    __syncthreads();
    int i = blockIdx.x * blockDim.x + tid;
    int stride = gridDim.x * blockDim.x;
    for (; i < n4; i += stride) {
        uint2 v = in[i];
        int cb = (i * 4) & 127;
        float4 s4 = *(const float4*)&scs[cb];
        float4 h4 = *(const float4*)&shs[cb];
        float y0 = bflo(v.x) * s4.x + h4.x;
        float y1 = bfhi(v.x) * s4.y + h4.y;
        float y2 = bflo(v.y) * s4.z + h4.z;
        float y3 = bfhi(v.y) * s4.w + h4.w;
        y0 = (y0 >= 0.f) ? y0 : 0.01f * y0;
        y1 = (y1 >= 0.f) ? y1 : 0.01f * y1;
        y2 = (y2 >= 0.f) ? y2 : 0.01f * y2;
        y3 = (y3 >= 0.f) ? y3 : 0.01f * y3;
        uint2 o;
        o.x = f2bf(y0) | (f2bf(y1) << 16);
        o.y = f2bf(y2) | (f2bf(y3) << 16);
        out[i] = o;
    }
}

// ---------------- fused BN finalize + BN + LeakyReLU + projection (layer 2) ----------------
__global__ void projbn2(const ushort* __restrict__ Cp, const ushort* __restrict__ Cq,
                        const float* __restrict__ STWl,
                        const float* __restrict__ gam, const float* __restrict__ bet,
                        const float* __restrict__ Wp, const float* __restrict__ bp,
                        float* __restrict__ out, int NN, int N) {
    int y = blockIdx.y;
    const uint* h = (const uint*)(y ? Cq : Cp);
    const float* W = Wp + y * 1024;
    const float* b = bp + y * 8;
    float* op = out + (size_t)y * N * 8;
    __shared__ float Wsh[1024];
    __shared__ float scs[128], shs[128];
    __shared__ float bsh[8];
    int tid = threadIdx.x;
    for (int i = tid; i < 1024; i += 256) Wsh[i] = W[i];
    if (tid < 128) {
        const float* base = STWl + (y ? 256 : 0);
        float s = 0.f, q = 0.f;
        #pragma unroll 8
        for (int cp = 0; cp < 32; ++cp) {
            s += base[cp * 512 + tid];
            q += base[cp * 512 + 128 + tid];
        }
        float m = s / (float)NN;
        float v = q / (float)NN - m * m;
        float rs = rsqrtf(v + 1e-5f);
        float sc = gam[y * 128 + tid] * rs;
        scs[tid] = sc;
        shs[tid] = bet[y * 128 + tid] - m * sc;
    }
    if (tid < 8) bsh[tid] = b[tid];
    __syncthreads();
    int idx = blockIdx.x * 256 + tid;
    if (idx >= N * LBL) return;
    int r = idx >> 3, c = idx & 7;
    const uint* hr = h + (size_t)r * 64;
    float s = bsh[c];
    #pragma unroll
    for (int k2 = 0; k2 < 64; ++k2) {
        uint v = hr[k2];
        float xa = bflo(v) * scs[2 * k2] + shs[2 * k2];
        float xb = bfhi(v) * scs[2 * k2 + 1] + shs[2 * k2 + 1];
        xa = (xa >= 0.f) ? xa : 0.01f * xa;
        xb = (xb >= 0.f) ? xb : 0.01f * xb;
        s += xa * Wsh[(2 * k2) * 8 + c] + xb * Wsh[(2 * k2 + 1) * 8 + c];
    }
    op[idx] = s;
}

// ---------------- host ----------------

extern "C" void kernel_launch(void* const* d_in, const int* in_sizes, int n_in,
                              void* d_out, int out_size, void* d_ws, size_t ws_size,
                              hipStream_t stream) {
    const float* x0 = (const float*)d_in[0];
    const float* x1 = (const float*)d_in[1];
    const float* Wn1 = (const float*)d_in[2];
    const float* Ws1 = (const float*)d_in[3];
    const float* Wu1 = (const float*)d_in[4];
    const float* Wn2 = (const float*)d_in[5];
    const float* Ws2 = (const float*)d_in[6];
    const float* Wu2 = (const float*)d_in[7];
    const float* bnn[2] = {(const float*)d_in[8], (const float*)d_in[11]};
    const float* bss[2] = {(const float*)d_in[9], (const float*)d_in[12]};
    const float* buu[2] = {(const float*)d_in[10], (const float*)d_in[13]};
    const float* gam[2] = {(const float*)d_in[14], (const float*)d_in[16]};
    const float* bet[2] = {(const float*)d_in[15], (const float*)d_in[17]};
    const float* Wp = (const float*)d_in[18];
    const float* bp = (const float*)d_in[19];
    const int* ei[3] = {(const int*)d_in[20], (const int*)d_in[21], (const int*)d_in[22]};

    const int N = in_sizes[0] / 128;
    const int E = in_sizes[20] / 2;
    const int NB = (N + (1 << BSH) - 1) >> BSH;
    float* out = (float*)d_out;

    char* wp_ = (char*)d_ws;
    auto carve = [&](size_t bytes) {
        char* r = wp_;
        wp_ += (bytes + 255) & ~(size_t)255;
        return r;
    };
    size_t nodeB = (size_t)N * 128 * sizeof(ushort);
    ushort* Cp = (ushort*)carve(nodeB);   // h0pre bf16 (pairs aliases this early)
    ushort* Cq = (ushort*)carve(nodeB);   // h1pre bf16
    ushort* Pb = (ushort*)carve(nodeB);
    ushort* Rb = (ushort*)carve(nodeB);
    ushort* Sb = (ushort*)carve(nodeB);
    ushort* X0b = (ushort*)carve(nodeB);
    ushort* X1b = (ushort*)carve(nodeB);
    ushort* x0b = (ushort*)carve(nodeB);
    ushort* x1b = (ushort*)carve(nodeB);
    ushort* FT = (ushort*)carve(10 * 16384 * 2);
    float* FC = (float*)carve(4 * 128 * 4);
    float* STW = (float*)carve(2 * 32 * 512 * 4);  // per-layer 32 shadow BN-stat copies
    int* offs = (int*)carve((size_t)3 * (N + 1) * 4);
    ushort* srcs = (ushort*)carve((size_t)3 * E * 2);
    int* bcnt = (int*)carve((size_t)3 * NB * 4);
    int* bso = (int*)carve((size_t)3 * (NB + 1) * 4);
    int* gcur = (int*)carve((size_t)3 * NB * 4);
    uint* pairs = (uint*)Cp;  // 3*E*4 = 6 MB <= nodeB (12.8 MB); dead before gemm writes Cp

    const int ag = (N + 15) / 16;
    const int gg = (N + 63) / 64;
    const int pg = (N * LBL + 255) / 256;
    const int bg = (E + 256 * BIN_CH - 1) / (256 * BIN_CH);

    hipMemsetAsync(bcnt, 0, (size_t)3 * NB * 4, stream);
    hipMemsetAsync(STW, 0, (size_t)2 * 32 * 512 * 4, stream);

    // fused prep: f2b + bucket hist + weight/bias fusion (single dispatch)
    prep<<<3202, 256, 0, stream>>>(
        (const float4*)x0, (const float4*)x1, (uint2*)x0b, (uint2*)x1b, N * 32,
        ei[0], ei[1], ei[2], E, NB, bcnt,
        Wn1, Ws1, Wu1, Wn2, Ws2, Wu2, FT,
        bnn[0], bss[0], buu[0], bnn[1], bss[1], buu[1], FC);

    bscan<<<1, 64, 0, stream>>>(bcnt, bso, gcur, NB);
    bin3<<<dim3(bg, 3), 256, 0, stream>>>(ei[0], ei[1], ei[2], E, NB, gcur, pairs);
    csr3<<<dim3(NB, 3), 256, 0, stream>>>(pairs, bso, E, N, NB, offs, srcs);

    const ushort* srcS[2][3] = {{x0b, x1b, x0b}, {X0b, X1b, X0b}};
    const ushort* dstX[2][2] = {{x0b, x1b}, {X0b, X1b}};

    for (int l = 0; l < 2; ++l) {
        const ushort* FA0T = FT + (size_t)(l * 5 + 0) * 16384;
        const ushort* FA1T = FT + (size_t)(l * 5 + 1) * 16384;
        const ushort* FA2T = FT + (size_t)(l * 5 + 2) * 16384;
        const ushort* FB1T = FT + (size_t)(l * 5 + 3) * 16384;
        const ushort* FB0T = FT + (size_t)(l * 5 + 4) * 16384;
        const float* fcH1 = FC + (l * 2 + 0) * 128;
        const float* fcH0 = FC + (l * 2 + 1) * 128;
        float* STWl = STW + (size_t)l * 32 * 512;

        agg3<<<dim3(ag, 3), 256, 0, stream>>>(srcS[l][0], srcS[l][1], srcS[l][2],
                                              (uint*)Pb, (uint*)Rb, (uint*)Sb,
                                              offs, srcs, N, E);

        // y=0: Cq = Pb@FA0 + x1@FB1 ; y=1: Cp = Rb@FA1 + Sb@FA2 + x0@FB0
        gemm2_mfma<<<dim3(gg, 2), 256, 0, stream>>>(
            Pb, FA0T, dstX[l][1], FB1T,
            Rb, FA1T, Sb, FA2T, dstX[l][0], FB0T,
            fcH1, fcH0, Cq, Cp, N, STWl);

        if (l == 0)
            bn_apply2<<<dim3(512, 2), 256, 0, stream>>>(Cp, X0b, Cq, X1b, STWl,
                                                        gam[0], bet[0], N, N * 32);
    }

    // layer-2 BN finalize + apply + projection fused
    projbn2<<<dim3(pg, 2), 256, 0, stream>>>(Cp, Cq, STW + 32 * 512,
                                             gam[1], bet[1], Wp, bp, out, N, N);
}

// Round 16
// 280.921 us; speedup vs baseline: 1.1591x; 1.0171x over previous
//
#include <hip/hip_runtime.h>

#define LBL 8
#define NBMAX 128
#define BSH 9            // 512 dsts per bucket
#define BCAP 8192        // LDS sort capacity per bucket (mean ~5100)

typedef __attribute__((ext_vector_type(8))) short short8;
typedef __attribute__((ext_vector_type(4))) float f32x4;

__device__ __forceinline__ uint f2bf(float x) {
    uint u = __float_as_uint(x);
    return (u + 0x7fffu + ((u >> 16) & 1u)) >> 16;
}
__device__ __forceinline__ float bflo(uint v) { return __uint_as_float(v << 16); }
__device__ __forceinline__ float bfhi(uint v) { return __uint_as_float(v & 0xffff0000u); }

// async global->LDS 16B per lane: dest = lds_base(wave-uniform) + lane*16
__device__ __forceinline__ void gload16(const ushort* g, ushort* l) {
    __builtin_amdgcn_global_load_lds((const __attribute__((address_space(1))) uint*)g,
                                     (__attribute__((address_space(3))) uint*)l, 16, 0, 0);
}

// ---------------- PREP: f2b (x2) + bucket hist (x3) + weight fusion, one dispatch ----------------
// block ranges: [0,1024) f2b | [1024,2560) bhist | [2560,3200) fuseW | [3200,3202) fuseB
__global__ __launch_bounds__(256) void prep(
    const float4* __restrict__ x0, const float4* __restrict__ x1,
    uint2* __restrict__ o0, uint2* __restrict__ o1, int n4,
    const int* __restrict__ e0, const int* __restrict__ e1, const int* __restrict__ e2,
    int E, int NB, int* __restrict__ bcnt,
    const float* __restrict__ Wn1, const float* __restrict__ Ws1, const float* __restrict__ Wu1,
    const float* __restrict__ Wn2, const float* __restrict__ Ws2, const float* __restrict__ Wu2,
    ushort* __restrict__ FT,
    const float* __restrict__ bn1, const float* __restrict__ bs1, const float* __restrict__ bu1,
    const float* __restrict__ bn2, const float* __restrict__ bs2, const float* __restrict__ bu2,
    float* __restrict__ FC) {
    __shared__ int h[NBMAX];
    int b = blockIdx.x;
    int tid = threadIdx.x;

    if (b < 1024) {                       // ---- fp32 -> bf16 ----
        int y = b >> 9;
        const float4* in = y ? x1 : x0;
        uint2* out = y ? o1 : o0;
        int i = (b & 511) * 256 + tid;
        int stride = 512 * 256;
        for (; i < n4; i += stride) {
            float4 v = in[i];
            uint2 o;
            o.x = f2bf(v.x) | (f2bf(v.y) << 16);
            o.y = f2bf(v.z) | (f2bf(v.w) << 16);
            out[i] = o;
        }
    } else if (b < 2560) {                // ---- coarse bucket histogram ----
        int bb = b - 1024;
        int m = bb / 512, sub = bb - m * 512;
        const int* dst = (m == 0 ? e0 : (m == 1 ? e1 : e2)) + E;
        if (tid < NB) h[tid] = 0;
        __syncthreads();
        int i = sub * 256 + tid, st = 512 * 256;
        for (; i < E; i += st) atomicAdd(&h[dst[i] >> BSH], 1);
        __syncthreads();
        if (tid < NB && h[tid]) atomicAdd(&bcnt[m * NB + tid], h[tid]);
    } else if (b < 3200) {                // ---- fuseW: 64 blocks per j5, 2 rows per block ----
        int bb = b - 2560;
        int j5 = bb >> 6, rem = bb & 63;
        int l = j5 / 5, t = j5 - l * 5;
        const float* Wn = l ? Wn2 : Wn1;
        const float* Ws = l ? Ws2 : Ws1;
        const float* Wu = l ? Wu2 : Wu1;
        const float *A0, *B0, *A1 = nullptr, *B1 = nullptr;
        float al;
        switch (t) {
            case 0: A0 = Wn;          B0 = Wu;          al = 1.0f; break;
            case 1: A0 = Wn + 16384;  B0 = Wu + 32768;  al = 0.5f; break;
            case 2: A0 = Wn + 32768;  B0 = Wu + 65536;  al = 0.5f; break;
            case 3: A0 = Ws;          B0 = Wu + 16384;  al = 1.0f; break;
            default:
                A0 = Ws + 16384; B0 = Wu + 49152;
                A1 = Ws + 32768; B1 = Wu + 81920;
                al = 0.5f; break;
        }
        int i = rem * 2 + (tid >> 7);
        int j = tid & 127;
        float s0 = 0, s1 = 0, s2 = 0, s3 = 0;
        #pragma unroll 4
        for (int k = 0; k < 128; k += 4) {
            s0 += A0[i * 128 + k]     * B0[k * 128 + j];
            s1 += A0[i * 128 + k + 1] * B0[(k + 1) * 128 + j];
            s2 += A0[i * 128 + k + 2] * B0[(k + 2) * 128 + j];
            s3 += A0[i * 128 + k + 3] * B0[(k + 3) * 128 + j];
        }
        if (A1) {
            #pragma unroll 4
            for (int k = 0; k < 128; k += 4) {
                s0 += A1[i * 128 + k]     * B1[k * 128 + j];
                s1 += A1[i * 128 + k + 1] * B1[(k + 1) * 128 + j];
                s2 += A1[i * 128 + k + 2] * B1[(k + 2) * 128 + j];
                s3 += A1[i * 128 + k + 3] * B1[(k + 3) * 128 + j];
            }
        }
        float r = al * ((s0 + s1) + (s2 + s3));
        FT[(size_t)j5 * 16384 + j * 128 + i] = (ushort)f2bf(r);
    } else {                              // ---- fuseB: 2 jobs per block ----
        int jb = (b - 3200) * 2 + (tid >> 7);
        int l = jb >> 1, which = jb & 1;
        const float* bn = l ? bn2 : bn1;
        const float* bs = l ? bs2 : bs1;
        const float* bu = l ? bu2 : bu1;
        const float* Wu = l ? Wu2 : Wu1;
        int j = tid & 127;
        float s = 0.f;
        if (which == 0) {
            s = bu[j];
            for (int k = 0; k < 128; ++k)
                s += bn[k] * Wu[k * 128 + j] + bs[k] * Wu[(128 + k) * 128 + j];
        } else {
            #pragma unroll
            for (int tt = 1; tt <= 2; ++tt) {
                const float* Wt = Wu + tt * 32768;
                float p = bu[tt * 128 + j];
                for (int k = 0; k < 128; ++k)
                    p += bn[tt * 128 + k] * Wt[k * 128 + j] + bs[tt * 128 + k] * Wt[(128 + k) * 128 + j];
                s += 0.5f * p;
            }
        }
        FC[jb * 128 + j] = s;
    }
}

// ---------------- CSR build: bin + fine sort (bucket scan computed locally per block) ----------------
// record: src (16b) | dst-low-9 << 16   (requires N <= 65536)
#define BIN_CH 16
__global__ __launch_bounds__(256) void bin3(const int* __restrict__ e0, const int* __restrict__ e1,
                                            const int* __restrict__ e2, int E, int NB,
                                            const int* __restrict__ bcnt,
                                            int* __restrict__ gcur, uint* __restrict__ pairs) {
    int m = blockIdx.y;
    const int* eb = (m == 0 ? e0 : (m == 1 ? e1 : e2));
    const int* src = eb;
    const int* dst = eb + E;
    uint* pp = pairs + (size_t)m * E;
    int* gc = gcur + m * NB;
    __shared__ int h[NBMAX], base[NBMAX], pos[NBMAX], bso[NBMAX];
    int tid = threadIdx.x;
    if (tid < NB) { h[tid] = 0; pos[tid] = 0; }
    if (tid == 0) {                      // local exclusive scan of this type's bucket counts
        int acc = 0;
        for (int q = 0; q < NB; ++q) {
            bso[q] = acc;
            acc += bcnt[m * NB + q];
        }
    }
    __syncthreads();
    int i0 = blockIdx.x * (256 * BIN_CH);
    uint pk[BIN_CH];
    int bk[BIN_CH];
    #pragma unroll
    for (int u = 0; u < BIN_CH; ++u) {
        int i = i0 + u * 256 + tid;
        bk[u] = -1;
        if (i < E) {
            int s = src[i], d = dst[i];
            bk[u] = d >> BSH;
            pk[u] = (uint)s | ((uint)(d & ((1 << BSH) - 1)) << 16);
            atomicAdd(&h[bk[u]], 1);
        }
    }
    __syncthreads();
    if (tid < NB && h[tid]) base[tid] = bso[tid] + atomicAdd(&gc[tid], h[tid]);
    __syncthreads();
    #pragma unroll
    for (int u = 0; u < BIN_CH; ++u) {
        if (bk[u] >= 0) {
            int p = base[bk[u]] + atomicAdd(&pos[bk[u]], 1);
            pp[p] = pk[u];
        }
    }
}

__global__ __launch_bounds__(256) void csr3(const uint* __restrict__ pairs, const int* __restrict__ bcnt,
                                            int E, int N, int NB,
                                            int* __restrict__ offs, ushort* __restrict__ srcs) {
    int m = blockIdx.y, b = blockIdx.x;
    const uint* pp = pairs + (size_t)m * E;
    __shared__ int gse[2];
    __shared__ int hist[1 << BSH], po[1 << BSH], off0[1 << BSH];
    __shared__ int lsort[BCAP];
    __shared__ int wsum[4];
    int tid = threadIdx.x;
    if (tid == 0) {                      // local scan: gstart for bucket b, gend = gstart + cnt_b
        int acc = 0;
        for (int q = 0; q < b; ++q) acc += bcnt[m * NB + q];
        gse[0] = acc;
        gse[1] = acc + bcnt[m * NB + b];
        if (b == NB - 1) {
            int tot = gse[1];
            offs[(size_t)m * (N + 1) + N] = tot;
        }
    }
    hist[tid] = 0;
    hist[tid + 256] = 0;
    __syncthreads();
    int gstart = gse[0];
    int cnt = gse[1] - gstart;
    if (cnt > BCAP) cnt = BCAP;
    int d0 = b << BSH;
    int dcnt = N - d0;
    if (dcnt > (1 << BSH)) dcnt = 1 << BSH;

    for (int i = tid; i < cnt; i += 256) atomicAdd(&hist[pp[gstart + i] >> 16], 1);
    __syncthreads();
    int a = hist[2 * tid], b2 = hist[2 * tid + 1];
    int s = a + b2;
    int lane = tid & 63, w = tid >> 6;
    #pragma unroll
    for (int o = 1; o < 64; o <<= 1) {
        int v = __shfl_up(s, o, 64);
        if (lane >= o) s += v;
    }
    if (lane == 63) wsum[w] = s;
    __syncthreads();
    int wp = 0;
    #pragma unroll
    for (int q = 0; q < 4; ++q)
        if (q < w) wp += wsum[q];
    int excl = wp + s - a - b2;
    off0[2 * tid] = excl; off0[2 * tid + 1] = excl + a;
    po[2 * tid] = excl;   po[2 * tid + 1] = excl + a;
    __syncthreads();
    for (int j = tid; j < dcnt; j += 256) offs[(size_t)m * (N + 1) + d0 + j] = gstart + off0[j];
    for (int i = tid; i < cnt; i += 256) {
        uint e = pp[gstart + i];
        int p = atomicAdd(&po[e >> 16], 1);
        if (p < BCAP) lsort[p] = (int)(e & 0xffffu);
    }
    __syncthreads();
    for (int i = tid; i < cnt; i += 256) srcs[(size_t)m * E + gstart + i] = (ushort)lsort[i];
}

// ---------------- segment mean: 4 rows/wave (16 lanes x uint4 = 256B row), 4-unrolled ----------------
__global__ void agg3(const ushort* __restrict__ s0, const ushort* __restrict__ s1,
                     const ushort* __restrict__ s2,
                     uint* __restrict__ o0, uint* __restrict__ o1, uint* __restrict__ o2,
                     const int* __restrict__ offs, const ushort* __restrict__ srcs,
                     int n, int E) {
    int m = blockIdx.y;
    const uint4* x = (const uint4*)(m == 0 ? s0 : (m == 1 ? s1 : s2));
    uint4* o = (uint4*)(m == 0 ? o0 : (m == 1 ? o1 : o2));
    const int* off = offs + (size_t)m * (n + 1);
    const ushort* sl = srcs + (size_t)m * E;

    int tid = threadIdx.x;
    int l16 = tid & 15;
    int row = blockIdx.x * 16 + (tid >> 4);
    if (row >= n) return;
    int s = off[row], e = off[row + 1];
    float a0 = 0, a1 = 0, a2 = 0, a3 = 0, a4 = 0, a5 = 0, a6 = 0, a7 = 0;
    int i = s;
    for (; i + 3 < e; i += 4) {
        int j0 = sl[i], j1 = sl[i + 1], j2 = sl[i + 2], j3 = sl[i + 3];
        uint4 v0 = x[(size_t)j0 * 16 + l16];
        uint4 v1 = x[(size_t)j1 * 16 + l16];
        uint4 v2 = x[(size_t)j2 * 16 + l16];
        uint4 v3 = x[(size_t)j3 * 16 + l16];
        a0 += (bflo(v0.x) + bflo(v1.x)) + (bflo(v2.x) + bflo(v3.x));
        a1 += (bfhi(v0.x) + bfhi(v1.x)) + (bfhi(v2.x) + bfhi(v3.x));
        a2 += (bflo(v0.y) + bflo(v1.y)) + (bflo(v2.y) + bflo(v3.y));
        a3 += (bfhi(v0.y) + bfhi(v1.y)) + (bfhi(v2.y) + bfhi(v3.y));
        a4 += (bflo(v0.z) + bflo(v1.z)) + (bflo(v2.z) + bflo(v3.z));
        a5 += (bfhi(v0.z) + bfhi(v1.z)) + (bfhi(v2.z) + bfhi(v3.z));
        a6 += (bflo(v0.w) + bflo(v1.w)) + (bflo(v2.w) + bflo(v3.w));
        a7 += (bfhi(v0.w) + bfhi(v1.w)) + (bfhi(v2.w) + bfhi(v3.w));
    }
    for (; i < e; ++i) {
        uint4 v = x[(size_t)sl[i] * 16 + l16];
        a0 += bflo(v.x); a1 += bfhi(v.x);
        a2 += bflo(v.y); a3 += bfhi(v.y);
        a4 += bflo(v.z); a5 += bfhi(v.z);
        a6 += bflo(v.w); a7 += bfhi(v.w);
    }
    int d = e - s;
    float inv = 1.f / (float)(d > 0 ? d : 1);
    uint4 r;
    r.x = f2bf(a0 * inv) | (f2bf(a1 * inv) << 16);
    r.y = f2bf(a2 * inv) | (f2bf(a3 * inv) << 16);
    r.z = f2bf(a4 * inv) | (f2bf(a5 * inv) << 16);
    r.w = f2bf(a6 * inv) | (f2bf(a7 * inv) << 16);
    o[(size_t)row * 16 + l16] = r;
}

// ---------------- batched MFMA GEMM: dbuf global_load_lds + LDS-transposed coalesced C store ----------------
__global__ __launch_bounds__(256) void gemm2_mfma(
    const ushort* __restrict__ Aq0, const ushort* __restrict__ Wq0,
    const ushort* __restrict__ Aq1, const ushort* __restrict__ Wq1,
    const ushort* __restrict__ Ap0, const ushort* __restrict__ Wp0,
    const ushort* __restrict__ Ap1, const ushort* __restrict__ Wp1,
    const ushort* __restrict__ Ap2, const ushort* __restrict__ Wp2,
    const float* __restrict__ biasq, const float* __restrict__ biasp,
    ushort* __restrict__ Cq, ushort* __restrict__ Cp, int M,
    float* __restrict__ STW) {
    __shared__ ushort As[2][64 * 128];
    int y = blockIdx.y;
    const float* bias = y ? biasp : biasq;
    ushort* C = y ? Cp : Cq;
    float* colsum = STW + (size_t)(blockIdx.x & 31) * 512 + (y ? 0 : 256);
    float* colsq = colsum + 128;

    int tid = threadIdx.x;
    int wid = tid >> 6;
    int lane = tid & 63;
    int l15 = lane & 15, lg = lane >> 4;
    int row0 = blockIdx.x * 64;
    int nIn = y ? 3 : 2;

    const ushort* Ax[3];
    const ushort* Wx[3];
    Ax[0] = y ? Ap0 : Aq0;  Wx[0] = y ? Wp0 : Wq0;
    Ax[1] = y ? Ap1 : Aq1;  Wx[1] = y ? Wp1 : Wq1;
    Ax[2] = Ap2;            Wx[2] = Wp2;

    auto stage = [&](const ushort* A, ushort* buf) {
        #pragma unroll
        for (int p = 0; p < 4; ++p) {
            int row = wid * 16 + p * 4 + (lane >> 4);
            int gr = row0 + row;
            if (gr > M - 1) gr = M - 1;
            const ushort* src = A + (size_t)gr * 128 + (((lane & 15) ^ (row & 7)) * 8);
            gload16(src, buf + (wid * 4 + p) * 512);
        }
    };

    f32x4 acc[4][2];
    #pragma unroll
    for (int rb = 0; rb < 4; ++rb)
        #pragma unroll
        for (int cb = 0; cb < 2; ++cb) acc[rb][cb] = (f32x4){0.f, 0.f, 0.f, 0.f};

    stage(Ax[0], As[0]);
    __syncthreads();
    int cur = 0;

    #pragma unroll
    for (int inp = 0; inp < 3; ++inp) {
        if (inp == 2 && nIn == 2) break;   // wave-uniform
        const ushort* W = Wx[inp];
        short8 bw[4][2];
        #pragma unroll
        for (int k0 = 0; k0 < 4; ++k0)
            #pragma unroll
            for (int cb = 0; cb < 2; ++cb)
                bw[k0][cb] = *(const short8*)(W + (size_t)(wid * 32 + cb * 16 + l15) * 128 + k0 * 32 + lg * 8);
        if (inp + 1 < nIn) stage(Ax[inp + 1], As[cur ^ 1]);
        #pragma unroll
        for (int k0 = 0; k0 < 4; ++k0) {
            short8 a[4];
            #pragma unroll
            for (int rb = 0; rb < 4; ++rb)
                a[rb] = *(const short8*)&As[cur][(rb * 16 + l15) * 128 + (((k0 * 4 + lg) ^ (l15 & 7)) * 8)];
            #pragma unroll
            for (int rb = 0; rb < 4; ++rb)
                #pragma unroll
                for (int cb = 0; cb < 2; ++cb)
                    acc[rb][cb] = __builtin_amdgcn_mfma_f32_16x16x32_bf16(a[rb], bw[k0][cb], acc[rb][cb], 0, 0, 0);
        }
        __syncthreads();             // also frees As for the epilogue transpose
        cur ^= 1;
    }

    // epilogue: bias + BN stats (regs) + bf16 pack into LDS[row][col]
    float ps[2] = {0.f, 0.f}, pq[2] = {0.f, 0.f};
    int colbase = wid * 32;
    ushort* T = As[0];
    #pragma unroll
    for (int cb = 0; cb < 2; ++cb) {
        int col = colbase + cb * 16 + l15;
        float b = bias[col];
        #pragma unroll
        for (int rb = 0; rb < 4; ++rb) {
            int lrow = rb * 16 + lg * 4;
            #pragma unroll
            for (int i = 0; i < 4; ++i) {
                float v = acc[rb][cb][i] + b;
                T[(lrow + i) * 128 + col] = (ushort)f2bf(v);
                if (row0 + lrow + i < M) {
                    ps[cb] += v;
                    pq[cb] += v * v;
                }
            }
        }
    }
    #pragma unroll
    for (int cb = 0; cb < 2; ++cb) {
        ps[cb] += __shfl_xor(ps[cb], 16, 64);
        ps[cb] += __shfl_xor(ps[cb], 32, 64);
        pq[cb] += __shfl_xor(pq[cb], 16, 64);
        pq[cb] += __shfl_xor(pq[cb], 32, 64);
    }
    if (lane < 16) {
        atomicAdd(&colsum[colbase + lane], ps[0]);
        atomicAdd(&colsq[colbase + lane], pq[0]);
        atomicAdd(&colsum[colbase + 16 + lane], ps[1]);
        atomicAdd(&colsq[colbase + 16 + lane], pq[1]);
    }
    __syncthreads();
    // coalesced C store: thread -> row tid>>2, 32-col chunk (tid&3)*32
    {
        int row = tid >> 2;
        int c0 = (tid & 3) * 32;
        int gr = row0 + row;
        if (gr < M) {
            uint4* dst = (uint4*)(C + (size_t)gr * 128 + c0);
            const uint4* src4 = (const uint4*)&T[row * 128 + c0];
            dst[0] = src4[0];
            dst[1] = src4[1];
            dst[2] = src4[2];
            dst[3] = src4[3];
        }
    }
}

// ---------------- BN apply + LeakyReLU with in-block stat finalize (layer 1) ----------------
__global__ void bn_apply2(const ushort* __restrict__ Cp, ushort* __restrict__ X0b,
                          const ushort* __restrict__ Cq, ushort* __restrict__ X1b,
                          const float* __restrict__ STWl,
                          const float* __restrict__ gam, const float* __restrict__ bet,
                          int N, int n4) {
    int y = blockIdx.y;
    const uint2* in = (const uint2*)(y ? Cq : Cp);
    uint2* out = (uint2*)(y ? X1b : X0b);
    __shared__ float scs[128], shs[128];
    int tid = threadIdx.x;
    if (tid < 128) {
        const float* base = STWl + (y ? 256 : 0);
        float s = 0.f, q = 0.f;
        #pragma unroll 8
        for (int cp = 0; cp < 32; ++cp) {
            s += base[cp * 512 + tid];
            q += base[cp * 512 + 128 + tid];
        }
        float m = s / (float)N;
        float v = q / (float)N - m * m;
        float rs = rsqrtf(v + 1e-5f);
        float sc = gam[y * 128 + tid] * rs;
        scs[tid] = sc;
        shs[tid] = bet[y * 128 + tid] - m * sc;
    }
    __syncthreads();
    int i = blockIdx.x * blockDim.x + tid;
    int stride = gridDim.x * blockDim.x;
    for (; i < n4; i += stride) {
        uint2 v = in[i];
        int cb = (i * 4) & 127;
        float4 s4 = *(const float4*)&scs[cb];
        float4 h4 = *(const float4*)&shs[cb];
        float y0 = bflo(v.x) * s4.x + h4.x;
        float y1 = bfhi(v.x) * s4.y + h4.y;
        float y2 = bflo(v.y) * s4.z + h4.z;
        float y3 = bfhi(v.y) * s4.w + h4.w;
        y0 = (y0 >= 0.f) ? y0 : 0.01f * y0;
        y1 = (y1 >= 0.f) ? y1 : 0.01f * y1;
        y2 = (y2 >= 0.f) ? y2 : 0.01f * y2;
        y3 = (y3 >= 0.f) ? y3 : 0.01f * y3;
        uint2 o;
        o.x = f2bf(y0) | (f2bf(y1) << 16);
        o.y = f2bf(y2) | (f2bf(y3) << 16);
        out[i] = o;
    }
}

// ---------------- fused BN finalize + BN + LeakyReLU + projection (layer 2) ----------------
__global__ void projbn2(const ushort* __restrict__ Cp, const ushort* __restrict__ Cq,
                        const float* __restrict__ STWl,
                        const float* __restrict__ gam, const float* __restrict__ bet,
                        const float* __restrict__ Wp, const float* __restrict__ bp,
                        float* __restrict__ out, int NN, int N) {
    int y = blockIdx.y;
    const uint* h = (const uint*)(y ? Cq : Cp);
    const float* W = Wp + y * 1024;
    const float* b = bp + y * 8;
    float* op = out + (size_t)y * N * 8;
    __shared__ float Wsh[1024];
    __shared__ float scs[128], shs[128];
    __shared__ float bsh[8];
    int tid = threadIdx.x;
    for (int i = tid; i < 1024; i += 256) Wsh[i] = W[i];
    if (tid < 128) {
        const float* base = STWl + (y ? 256 : 0);
        float s = 0.f, q = 0.f;
        #pragma unroll 8
        for (int cp = 0; cp < 32; ++cp) {
            s += base[cp * 512 + tid];
            q += base[cp * 512 + 128 + tid];
        }
        float m = s / (float)NN;
        float v = q / (float)NN - m * m;
        float rs = rsqrtf(v + 1e-5f);
        float sc = gam[y * 128 + tid] * rs;
        scs[tid] = sc;
        shs[tid] = bet[y * 128 + tid] - m * sc;
    }
    if (tid < 8) bsh[tid] = b[tid];
    __syncthreads();
    int idx = blockIdx.x * 256 + tid;
    if (idx >= N * LBL) return;
    int r = idx >> 3, c = idx & 7;
    const uint* hr = h + (size_t)r * 64;
    float s = bsh[c];
    #pragma unroll
    for (int k2 = 0; k2 < 64; ++k2) {
        uint v = hr[k2];
        float xa = bflo(v) * scs[2 * k2] + shs[2 * k2];
        float xb = bfhi(v) * scs[2 * k2 + 1] + shs[2 * k2 + 1];
        xa = (xa >= 0.f) ? xa : 0.01f * xa;
        xb = (xb >= 0.f) ? xb : 0.01f * xb;
        s += xa * Wsh[(2 * k2) * 8 + c] + xb * Wsh[(2 * k2 + 1) * 8 + c];
    }
    op[idx] = s;
}

// ---------------- host ----------------

extern "C" void kernel_launch(void* const* d_in, const int* in_sizes, int n_in,
                              void* d_out, int out_size, void* d_ws, size_t ws_size,
                              hipStream_t stream) {
    const float* x0 = (const float*)d_in[0];
    const float* x1 = (const float*)d_in[1];
    const float* Wn1 = (const float*)d_in[2];
    const float* Ws1 = (const float*)d_in[3];
    const float* Wu1 = (const float*)d_in[4];
    const float* Wn2 = (const float*)d_in[5];
    const float* Ws2 = (const float*)d_in[6];
    const float* Wu2 = (const float*)d_in[7];
    const float* bnn[2] = {(const float*)d_in[8], (const float*)d_in[11]};
    const float* bss[2] = {(const float*)d_in[9], (const float*)d_in[12]};
    const float* buu[2] = {(const float*)d_in[10], (const float*)d_in[13]};
    const float* gam[2] = {(const float*)d_in[14], (const float*)d_in[16]};
    const float* bet[2] = {(const float*)d_in[15], (const float*)d_in[17]};
    const float* Wp = (const float*)d_in[18];
    const float* bp = (const float*)d_in[19];
    const int* ei[3] = {(const int*)d_in[20], (const int*)d_in[21], (const int*)d_in[22]};

    const int N = in_sizes[0] / 128;
    const int E = in_sizes[20] / 2;
    const int NB = (N + (1 << BSH) - 1) >> BSH;
    float* out = (float*)d_out;

    char* wp_ = (char*)d_ws;
    auto carve = [&](size_t bytes) {
        char* r = wp_;
        wp_ += (bytes + 255) & ~(size_t)255;
        return r;
    };
    size_t nodeB = (size_t)N * 128 * sizeof(ushort);
    ushort* Cp = (ushort*)carve(nodeB);   // h0pre bf16 (pairs aliases this early)
    ushort* Cq = (ushort*)carve(nodeB);   // h1pre bf16
    ushort* Pb = (ushort*)carve(nodeB);
    ushort* Rb = (ushort*)carve(nodeB);
    ushort* Sb = (ushort*)carve(nodeB);
    ushort* X0b = (ushort*)carve(nodeB);
    ushort* X1b = (ushort*)carve(nodeB);
    ushort* x0b = (ushort*)carve(nodeB);
    ushort* x1b = (ushort*)carve(nodeB);
    ushort* FT = (ushort*)carve(10 * 16384 * 2);
    float* FC = (float*)carve(4 * 128 * 4);
    // contiguous zero-init region: STW (2 layers) | bcnt | gcur
    float* STW = (float*)carve(2 * 32 * 512 * 4);
    int* bcnt = (int*)carve((size_t)3 * NBMAX * 4);
    int* gcur = (int*)carve((size_t)3 * NBMAX * 4);
    size_t zspan = (char*)(gcur + 3 * NBMAX) - (char*)STW;
    int* offs = (int*)carve((size_t)3 * (N + 1) * 4);
    ushort* srcs = (ushort*)carve((size_t)3 * E * 2);
    uint* pairs = (uint*)Cp;  // 3*E*4 = 6 MB <= nodeB (12.8 MB); dead before gemm writes Cp

    const int ag = (N + 15) / 16;
    const int gg = (N + 63) / 64;
    const int pg = (N * LBL + 255) / 256;
    const int bg = (E + 256 * BIN_CH - 1) / (256 * BIN_CH);

    hipMemsetAsync(STW, 0, zspan, stream);

    // fused prep: f2b + bucket hist + weight/bias fusion (single dispatch)
    prep<<<3202, 256, 0, stream>>>(
        (const float4*)x0, (const float4*)x1, (uint2*)x0b, (uint2*)x1b, N * 32,
        ei[0], ei[1], ei[2], E, NB, bcnt,
        Wn1, Ws1, Wu1, Wn2, Ws2, Wu2, FT,
        bnn[0], bss[0], buu[0], bnn[1], bss[1], buu[1], FC);

    bin3<<<dim3(bg, 3), 256, 0, stream>>>(ei[0], ei[1], ei[2], E, NB, bcnt, gcur, pairs);
    csr3<<<dim3(NB, 3), 256, 0, stream>>>(pairs, bcnt, E, N, NB, offs, srcs);

    const ushort* srcS[2][3] = {{x0b, x1b, x0b}, {X0b, X1b, X0b}};
    const ushort* dstX[2][2] = {{x0b, x1b}, {X0b, X1b}};

    for (int l = 0; l < 2; ++l) {
        const ushort* FA0T = FT + (size_t)(l * 5 + 0) * 16384;
        const ushort* FA1T = FT + (size_t)(l * 5 + 1) * 16384;
        const ushort* FA2T = FT + (size_t)(l * 5 + 2) * 16384;
        const ushort* FB1T = FT + (size_t)(l * 5 + 3) * 16384;
        const ushort* FB0T = FT + (size_t)(l * 5 + 4) * 16384;
        const float* fcH1 = FC + (l * 2 + 0) * 128;
        const float* fcH0 = FC + (l * 2 + 1) * 128;
        float* STWl = STW + (size_t)l * 32 * 512;

        agg3<<<dim3(ag, 3), 256, 0, stream>>>(srcS[l][0], srcS[l][1], srcS[l][2],
                                              (uint*)Pb, (uint*)Rb, (uint*)Sb,
                                              offs, srcs, N, E);

        // y=0: Cq = Pb@FA0 + x1@FB1 ; y=1: Cp = Rb@FA1 + Sb@FA2 + x0@FB0
        gemm2_mfma<<<dim3(gg, 2), 256, 0, stream>>>(
            Pb, FA0T, dstX[l][1], FB1T,
            Rb, FA1T, Sb, FA2T, dstX[l][0], FB0T,
            fcH1, fcH0, Cq, Cp, N, STWl);

        if (l == 0)
            bn_apply2<<<dim3(512, 2), 256, 0, stream>>>(Cp, X0b, Cq, X1b, STWl,
                                                        gam[0], bet[0], N, N * 32);
    }

    // layer-2 BN finalize + apply + projection fused
    projbn2<<<dim3(pg, 2), 256, 0, stream>>>(Cp, Cq, STW + 32 * 512,
                                             gam[1], bet[1], Wp, bp, out, N, N);
}